// Round 8
// baseline (643.234 us; speedup 1.0000x reference)
//
#include <hip/hip_runtime.h>
#include <hip/hip_bf16.h>

typedef __bf16 bf16;
typedef __bf16 bf16x4 __attribute__((ext_vector_type(4)));
typedef __bf16 bf16x8 __attribute__((ext_vector_type(8)));
typedef float f32x4 __attribute__((ext_vector_type(4)));

#define NN 1024
#define GH 128
#define MROWS 8192  // 8*1024

static __device__ __forceinline__ f32x4 mfma16(bf16x8 a, bf16x8 b, f32x4 c) {
    return __builtin_amdgcn_mfma_f32_16x16x32_bf16(a, b, c, 0, 0, 0);
}

// ---------------- hand-rolled grid barrier (tree: 8x64 + 1) ----------------
// bar[batch*16] arrival counters (8, 64B apart); bar[128] batch-done count; bar[144] generation.
// Requires all 512 blocks resident (cooperative launch guarantees).
static __device__ __forceinline__ void gbar(unsigned* bar, int batch) {
    __syncthreads();  // drains each wave's outstanding stores
    if (threadIdx.x == 0) {
        unsigned* genp = bar + 144;
        unsigned g = __hip_atomic_load(genp, __ATOMIC_ACQUIRE, __HIP_MEMORY_SCOPE_AGENT);
        __threadfence();  // release: write back this XCD's dirty L2 lines
        bool resetter = false;
        if (atomicAdd(bar + batch * 16, 1u) == 63u) {
            if (atomicAdd(bar + 128, 1u) == 7u) {
#pragma unroll
                for (int i = 0; i < 8; ++i) atomicExch(bar + i * 16, 0u);
                atomicExch(bar + 128, 0u);
                __threadfence();
                atomicAdd(genp, 1u);
                resetter = true;
            }
        }
        if (!resetter) {
            while (__hip_atomic_load(genp, __ATOMIC_ACQUIRE, __HIP_MEMORY_SCOPE_AGENT) == g)
                __builtin_amdgcn_s_sleep(2);
        }
    }
    __syncthreads();
    __threadfence();  // acquire: invalidate stale cached copies before reading peers' data
}

// ---------------- fused layer phase (mega): T = A01_b @ Xt_b ; [U=T@W] ; v=relu(D*U+b) ----------------
template <bool HASW, bool WRITEH>
static __device__ __forceinline__ void fused_phase2(
        int m0, int batch, int tid,
        const bf16* A01, const bf16* Xt, const bf16* WtL,
        const float* dinv, const float* bias, bf16* Hst, float* oacc,
        f32x4* red, float* vbuf, bf16* Ths, bf16* Tls) {
    int wave = tid >> 6, lane = tid & 63;
    int kh = wave >> 1, ch = wave & 1;
    int lrow = lane & 15, lk = (lane >> 4) * 8;
    constexpr int KH = NN / 4;
    int kb = kh * KH;
    const bf16* Ap = A01 + (size_t)(m0 + lrow) * NN + kb + lk;
    const bf16* Bp = Xt + (size_t)(ch * 64 + lrow) * MROWS + batch * NN + kb + lk;
    f32x4 acc[4] = {};
#pragma unroll 4
    for (int k = 0; k < KH; k += 32) {
        bf16x8 a = *reinterpret_cast<const bf16x8*>(Ap + k);
#pragma unroll
        for (int f = 0; f < 4; ++f) {
            bf16x8 bb = *reinterpret_cast<const bf16x8*>(Bp + (size_t)f * 16 * MROWS + k);
            acc[f] = mfma16(a, bb, acc[f]);
        }
    }
    if (kh != 0) {
        int si = (((kh - 1) * 2 + ch) * 64 + lane) * 4;
#pragma unroll
        for (int f = 0; f < 4; ++f) red[si + f] = acc[f];
    }
    __syncthreads();
    if (kh == 0) {
#pragma unroll
        for (int p = 0; p < 3; ++p) {
            int si = ((p * 2 + ch) * 64 + lane) * 4;
#pragma unroll
            for (int f = 0; f < 4; ++f) acc[f] += red[si + f];
        }
    }
    if constexpr (!HASW) {
        __syncthreads();  // red reads done before vbuf (aliased) writes
        if (kh == 0) {
            int rl = (lane >> 4) * 4;
            int rbase = m0 + rl;
            float4 d4 = *reinterpret_cast<const float4*>(&dinv[rbase]);
#pragma unroll
            for (int f = 0; f < 4; ++f) {
                int col = ch * 64 + f * 16 + lrow;
                float bv = bias[col];
                float v0 = fmaxf(acc[f][0] * d4.x + bv, 0.f);
                float v1 = fmaxf(acc[f][1] * d4.y + bv, 0.f);
                float v2 = fmaxf(acc[f][2] * d4.z + bv, 0.f);
                float v3 = fmaxf(acc[f][3] * d4.w + bv, 0.f);
                vbuf[(rl + 0) * GH + col] = v0;
                vbuf[(rl + 1) * GH + col] = v1;
                vbuf[(rl + 2) * GH + col] = v2;
                vbuf[(rl + 3) * GH + col] = v3;
                bf16x4 h4;
                h4[0] = (bf16)(v0 * d4.x); h4[1] = (bf16)(v1 * d4.y);
                h4[2] = (bf16)(v2 * d4.z); h4[3] = (bf16)(v3 * d4.w);
                *reinterpret_cast<bf16x4*>(Hst + (size_t)col * MROWS + rbase) = h4;
            }
        }
        __syncthreads();
        int r0 = (lane >> 4) * 4;
        int ocol = wave * 16 + lrow;
#pragma unroll
        for (int r = 0; r < 4; ++r) oacc[r] += 0.25f * vbuf[(r0 + r) * GH + ocol];
    } else {
        if (kh == 0) {
            // store T as hi+lo bf16 (preserves f32 accuracy through MFMA epilogue)
#pragma unroll
            for (int f = 0; f < 4; ++f) {
                int tcol = ch * 64 + f * 16 + lrow;
#pragma unroll
                for (int r = 0; r < 4; ++r) {
                    int trow = (lane >> 4) * 4 + r;
                    float tv = acc[f][r];
                    bf16 hi = (bf16)tv;
                    int ei = trow * 128 + (tcol ^ ((trow & 7) << 3));
                    Ths[ei] = hi;
                    Tls[ei] = (bf16)(tv - (float)hi);
                }
            }
        }
        __syncthreads();
        f32x4 u = {};
        int wcol = wave * 16 + lrow;
#pragma unroll
        for (int ks = 0; ks < 4; ++ks) {
            int e0 = ks * 32 + lk;
            int te = lrow * 128 + (e0 ^ ((lrow & 7) << 3));
            bf16x8 thi = *reinterpret_cast<const bf16x8*>(&Ths[te]);
            bf16x8 tlo = *reinterpret_cast<const bf16x8*>(&Tls[te]);
            bf16x8 wv = *reinterpret_cast<const bf16x8*>(WtL + (size_t)wcol * GH + e0);
            u = mfma16(thi, wv, u);
            u = mfma16(tlo, wv, u);
        }
        int r0 = (lane >> 4) * 4;
        float4 d4 = *reinterpret_cast<const float4*>(&dinv[m0 + r0]);
        float bv = bias[wcol];
        float v0 = fmaxf(u[0] * d4.x + bv, 0.f);
        float v1 = fmaxf(u[1] * d4.y + bv, 0.f);
        float v2 = fmaxf(u[2] * d4.z + bv, 0.f);
        float v3 = fmaxf(u[3] * d4.w + bv, 0.f);
        oacc[0] += 0.25f * v0; oacc[1] += 0.25f * v1;
        oacc[2] += 0.25f * v2; oacc[3] += 0.25f * v3;
        if constexpr (WRITEH) {
            bf16x4 h4;
            h4[0] = (bf16)(v0 * d4.x); h4[1] = (bf16)(v1 * d4.y);
            h4[2] = (bf16)(v2 * d4.z); h4[3] = (bf16)(v3 * d4.w);
            *reinterpret_cast<bf16x4*>(Hst + (size_t)wcol * MROWS + m0 + r0) = h4;
        }
    }
}

// ---------------- mega2: 512 blocks x 512 threads, custom barrier, XCD-batch-locked ----------------
__global__ __launch_bounds__(512, 4) void mega2_kernel(
        const int* rpa, const float* aa,
        const float* W0f, const float* W1f, const float* W2f, const float* W3f,
        const float* b1, const float* b2, const float* b3, const float* b4,
        bf16* A01, float* dinv,
        bf16* Wt0, bf16* Wt1, bf16* Wt2, bf16* Wt3,
        bf16* Xt, bf16* HstA, bf16* HstB, float* outp, unsigned* bar) {
    __shared__ char smem[32768];
    f32x4* red  = (f32x4*)smem;            // 24KB split-K partials
    float* vbuf = (float*)smem;            // 8KB aliased (layer-1 redistribute)
    bf16*  Ths  = (bf16*)(smem + 24576);   // 4KB
    bf16*  Tls  = (bf16*)(smem + 28672);   // 4KB

    int s = blockIdx.x, tid = threadIdx.x;
    int Lb = (s & 7) * 64 + (s >> 3);      // XCD(s)=s%8 == batch -> L2-local flows
    int batch = s & 7;
    int m0 = Lb * 16;
    int wave = tid >> 6, lane = tid & 63;
    float oacc[4] = {0.f, 0.f, 0.f, 0.f};

    // ---- P0: A01 (exact 0/1 bf16, diag=1) + dinv for own 16 rows; weight transposes ----
    {
        int r = tid >> 5;                  // 0..15
        int row = m0 + r;
        int i = row & (NN - 1);
        int l32 = tid & 31;
        const int4* p = reinterpret_cast<const int4*>(rpa + (size_t)row * NN);
        bf16* arow = A01 + (size_t)row * NN;
        int cnt = 0;
#pragma unroll
        for (int it = 0; it < 8; ++it) {
            int c4 = l32 + it * 32;
            int4 v = p[c4];
            int j = c4 * 4;
            int a0 = (v.x != 0), a1 = (v.y != 0), a2 = (v.z != 0), a3 = (v.w != 0);
            cnt += (a0 & (j + 0 != i)) + (a1 & (j + 1 != i)) +
                   (a2 & (j + 2 != i)) + (a3 & (j + 3 != i));
            bf16x4 o;
            o[0] = (bf16)((a0 | (j + 0 == i)) ? 1.f : 0.f);
            o[1] = (bf16)((a1 | (j + 1 == i)) ? 1.f : 0.f);
            o[2] = (bf16)((a2 | (j + 2 == i)) ? 1.f : 0.f);
            o[3] = (bf16)((a3 | (j + 3 == i)) ? 1.f : 0.f);
            *reinterpret_cast<bf16x4*>(arow + j) = o;
        }
#pragma unroll
        for (int off = 16; off > 0; off >>= 1) cnt += __shfl_xor(cnt, off, 64);
        if (l32 == 0) dinv[row] = rsqrtf((float)(cnt + 1));  // +1 self-loop
        int gid = s * 512 + tid;
        if (gid < 22528) {
            const float* W; bf16* T; int K; int local;
            if (gid < 16384)      { W = W0f; T = Wt0; K = NN; local = gid; }
            else if (gid < 18432) { W = W1f; T = Wt1; K = GH; local = gid - 16384; }
            else if (gid < 20480) { W = W2f; T = Wt2; K = GH; local = gid - 18432; }
            else                  { W = W3f; T = Wt3; K = GH; local = gid - 20480; }
            int n = local & 127, k0 = (local >> 7) * 8;
            bf16x8 o;
#pragma unroll
            for (int ii = 0; ii < 8; ++ii) o[ii] = (bf16)W[(size_t)(k0 + ii) * GH + n];
            *reinterpret_cast<bf16x8*>(T + (size_t)n * K + k0) = o;
        }
    }
    gbar(bar, batch);

    // ---- P1: Xt[n][m] = bf16(dinv[m] * sum_k aa[m][k] * Wt0[n][k]) ----
    {
        int kh = wave >> 1, ch = wave & 1;
        int lrow = lane & 15, lk = (lane >> 4) * 8;
        constexpr int KH = NN / 4;
        int kb = kh * KH;
        const bf16*  Bp = Wt0 + (size_t)(ch * 64 + lrow) * NN + kb + lk;
        const float* Ap = aa + (size_t)(m0 + lrow) * NN + kb + lk;
        f32x4 acc[4] = {};
#pragma unroll 2
        for (int k = 0; k < KH; k += 32) {
            float4 a0 = *reinterpret_cast<const float4*>(Ap + k);
            float4 a1 = *reinterpret_cast<const float4*>(Ap + k + 4);
            bf16x8 a;
            a[0] = (bf16)a0.x; a[1] = (bf16)a0.y; a[2] = (bf16)a0.z; a[3] = (bf16)a0.w;
            a[4] = (bf16)a1.x; a[5] = (bf16)a1.y; a[6] = (bf16)a1.z; a[7] = (bf16)a1.w;
#pragma unroll
            for (int f = 0; f < 4; ++f) {
                bf16x8 bb = *reinterpret_cast<const bf16x8*>(Bp + (size_t)f * 16 * NN + k);
                acc[f] = mfma16(a, bb, acc[f]);
            }
        }
        if (kh != 0) {
            int si = (((kh - 1) * 2 + ch) * 64 + lane) * 4;
#pragma unroll
            for (int f = 0; f < 4; ++f) red[si + f] = acc[f];
        }
        __syncthreads();
        if (kh == 0) {
#pragma unroll
            for (int p = 0; p < 3; ++p) {
                int si = ((p * 2 + ch) * 64 + lane) * 4;
#pragma unroll
                for (int f = 0; f < 4; ++f) acc[f] += red[si + f];
            }
            int rbase = m0 + (lane >> 4) * 4;
            float4 d4 = *reinterpret_cast<const float4*>(&dinv[rbase]);
#pragma unroll
            for (int f = 0; f < 4; ++f) {
                int col = ch * 64 + f * 16 + lrow;
                bf16x4 o;
                o[0] = (bf16)(acc[f][0] * d4.x);
                o[1] = (bf16)(acc[f][1] * d4.y);
                o[2] = (bf16)(acc[f][2] * d4.z);
                o[3] = (bf16)(acc[f][3] * d4.w);
                *reinterpret_cast<bf16x4*>(Xt + (size_t)col * MROWS + rbase) = o;
            }
        }
    }
    gbar(bar, batch);

    // ---- P2..P5: four GCN layers, out accumulated in registers ----
    fused_phase2<false, true>(m0, batch, tid, A01, Xt,   Wt1, dinv, b1, HstA, oacc, red, vbuf, Ths, Tls);
    gbar(bar, batch);
    fused_phase2<true,  true>(m0, batch, tid, A01, HstA, Wt1, dinv, b2, HstB, oacc, red, vbuf, Ths, Tls);
    gbar(bar, batch);
    fused_phase2<true,  true>(m0, batch, tid, A01, HstB, Wt2, dinv, b3, HstA, oacc, red, vbuf, Ths, Tls);
    gbar(bar, batch);
    fused_phase2<true, false>(m0, batch, tid, A01, HstA, Wt3, dinv, b4, HstB, oacc, red, vbuf, Ths, Tls);

    // ---- final: write out (f32) ----
    {
        int r0 = (lane >> 4) * 4;
        int ocol = wave * 16 + (lane & 15);
#pragma unroll
        for (int r = 0; r < 4; ++r)
            outp[(size_t)(m0 + r0 + r) * GH + ocol] = oacc[r];
    }
}

// ============================ FALLBACK (round-5, verified) ============================

__global__ __launch_bounds__(256) void prep_wtrans_kernel(
        const int* __restrict__ rpa,
        const float* __restrict__ W0, const float* __restrict__ W1,
        const float* __restrict__ W2, const float* __restrict__ W3,
        bf16* __restrict__ A01, float* __restrict__ dinv,
        bf16* __restrict__ T0, bf16* __restrict__ T1,
        bf16* __restrict__ T2, bf16* __restrict__ T3) {
    int bid = blockIdx.x;
    if (bid < 2048) {
        int row  = bid * 4 + (threadIdx.x >> 6);
        int lane = threadIdx.x & 63;
        int i = row & (NN - 1);
        const int4* p = reinterpret_cast<const int4*>(rpa + (size_t)row * NN);
        bf16* arow = A01 + (size_t)row * NN;
        int cnt = 0;
#pragma unroll
        for (int it = 0; it < 4; ++it) {
            int4 v = p[lane + it * 64];
            int j = (lane + it * 64) * 4;
            int a0 = (v.x != 0), a1 = (v.y != 0), a2 = (v.z != 0), a3 = (v.w != 0);
            cnt += (a0 & (j + 0 != i)) + (a1 & (j + 1 != i)) +
                   (a2 & (j + 2 != i)) + (a3 & (j + 3 != i));
            bf16x4 o;
            o[0] = (bf16)((a0 | (j + 0 == i)) ? 1.f : 0.f);
            o[1] = (bf16)((a1 | (j + 1 == i)) ? 1.f : 0.f);
            o[2] = (bf16)((a2 | (j + 2 == i)) ? 1.f : 0.f);
            o[3] = (bf16)((a3 | (j + 3 == i)) ? 1.f : 0.f);
            *reinterpret_cast<bf16x4*>(arow + j) = o;
        }
#pragma unroll
        for (int off = 32; off > 0; off >>= 1) cnt += __shfl_down(cnt, off, 64);
        if (lane == 0) dinv[row] = rsqrtf((float)(cnt + 1));
    } else {
        int t = (bid - 2048) * 256 + threadIdx.x;
        const float* W; bf16* T; int K; int local;
        if (t < 16384)      { W = W0; T = T0; K = NN; local = t; }
        else if (t < 18432) { W = W1; T = T1; K = GH; local = t - 16384; }
        else if (t < 20480) { W = W2; T = T2; K = GH; local = t - 18432; }
        else                { W = W3; T = T3; K = GH; local = t - 20480; }
        int n = local & 127, k0 = (local >> 7) * 8;
        bf16x8 o;
#pragma unroll
        for (int ii = 0; ii < 8; ++ii) o[ii] = (bf16)W[(size_t)(k0 + ii) * GH + n];
        *reinterpret_cast<bf16x8*>(T + (size_t)n * K + k0) = o;
    }
}

template <int K, bool AF32>
__global__ __launch_bounds__(512, 4) void gemm_kernel(const void* __restrict__ Av,
                                                      const bf16* __restrict__ Wt,
                                                      const float* __restrict__ dinv,
                                                      bf16* __restrict__ Zt) {
    __shared__ f32x4 red[1536];
    int wave = threadIdx.x >> 6, lane = threadIdx.x & 63;
    int kh = wave >> 1, ch = wave & 1;
    int lrow = lane & 15, lk = (lane >> 4) * 8;
    int m0 = blockIdx.x * 16;
    constexpr int KH = K / 4;
    int kb = kh * KH;
    const bf16* Bp = Wt + (size_t)(ch * 64 + lrow) * K + kb + lk;
    f32x4 acc[4] = {};
    if constexpr (AF32) {
        const float* Ap = (const float*)Av + (size_t)(m0 + lrow) * K + kb + lk;
#pragma unroll 2
        for (int k = 0; k < KH; k += 32) {
            float4 a0 = *reinterpret_cast<const float4*>(Ap + k);
            float4 a1 = *reinterpret_cast<const float4*>(Ap + k + 4);
            bf16x8 a;
            a[0] = (bf16)a0.x; a[1] = (bf16)a0.y; a[2] = (bf16)a0.z; a[3] = (bf16)a0.w;
            a[4] = (bf16)a1.x; a[5] = (bf16)a1.y; a[6] = (bf16)a1.z; a[7] = (bf16)a1.w;
#pragma unroll
            for (int f = 0; f < 4; ++f) {
                bf16x8 bb = *reinterpret_cast<const bf16x8*>(Bp + (size_t)f * 16 * K + k);
                acc[f] = mfma16(a, bb, acc[f]);
            }
        }
    } else {
        const bf16* Ap = (const bf16*)Av + (size_t)(m0 + lrow) * K + kb + lk;
#pragma unroll 4
        for (int k = 0; k < KH; k += 32) {
            bf16x8 a = *reinterpret_cast<const bf16x8*>(Ap + k);
#pragma unroll
            for (int f = 0; f < 4; ++f) {
                bf16x8 bb = *reinterpret_cast<const bf16x8*>(Bp + (size_t)f * 16 * K + k);
                acc[f] = mfma16(a, bb, acc[f]);
            }
        }
    }
    if (kh != 0) {
        int si = (((kh - 1) * 2 + ch) * 64 + lane) * 4;
#pragma unroll
        for (int f = 0; f < 4; ++f) red[si + f] = acc[f];
    }
    __syncthreads();
    if (kh == 0) {
#pragma unroll
        for (int p = 0; p < 3; ++p) {
            int si = ((p * 2 + ch) * 64 + lane) * 4;
#pragma unroll
            for (int f = 0; f < 4; ++f) acc[f] += red[si + f];
        }
        int rbase = m0 + (lane >> 4) * 4;
        float4 d4 = *reinterpret_cast<const float4*>(&dinv[rbase]);
#pragma unroll
        for (int f = 0; f < 4; ++f) {
            int col = ch * 64 + f * 16 + lrow;
            bf16x4 o;
            o[0] = (bf16)(acc[f][0] * d4.x);
            o[1] = (bf16)(acc[f][1] * d4.y);
            o[2] = (bf16)(acc[f][2] * d4.z);
            o[3] = (bf16)(acc[f][3] * d4.w);
            *reinterpret_cast<bf16x4*>(Zt + (size_t)col * MROWS + rbase) = o;
        }
    }
}

template <int MODE, bool HASW>
__global__ __launch_bounds__(512, 4) void fused_kernel(const bf16* __restrict__ A01,
                                                       const bf16* __restrict__ Xt,
                                                       const bf16* __restrict__ Wt,
                                                       const float* __restrict__ dinv,
                                                       const float* __restrict__ bias,
                                                       bf16* __restrict__ Hst,
                                                       float* __restrict__ outp) {
    __shared__ f32x4 red[1536];
    __shared__ bf16 Wlds[16384];
    __shared__ bf16 Ths[2048];
    __shared__ bf16 Tls[2048];
    int wave = threadIdx.x >> 6, lane = threadIdx.x & 63;
    int kh = wave >> 1, ch = wave & 1;
    int lrow = lane & 15, lk = (lane >> 4) * 8;
    int m0 = blockIdx.x * 16;
    int b  = blockIdx.x >> 6;
    if constexpr (HASW) {
        const bf16x8* src = reinterpret_cast<const bf16x8*>(Wt);
        bf16x8* dst = reinterpret_cast<bf16x8*>(Wlds);
#pragma unroll
        for (int i = 0; i < 4; ++i) {
            int idx = threadIdx.x * 4 + i;
            dst[idx ^ ((idx >> 4) & 7)] = src[idx];
        }
    }
    constexpr int KH = NN / 4;
    int kb = kh * KH;
    const bf16* Ap = A01 + (size_t)(m0 + lrow) * NN + kb + lk;
    const bf16* Bp = Xt + (size_t)(ch * 64 + lrow) * MROWS + b * NN + kb + lk;
    f32x4 acc[4] = {};
#pragma unroll 4
    for (int k = 0; k < KH; k += 32) {
        bf16x8 a = *reinterpret_cast<const bf16x8*>(Ap + k);
#pragma unroll
        for (int f = 0; f < 4; ++f) {
            bf16x8 bb = *reinterpret_cast<const bf16x8*>(Bp + (size_t)f * 16 * MROWS + k);
            acc[f] = mfma16(a, bb, acc[f]);
        }
    }
    if (kh != 0) {
        int si = (((kh - 1) * 2 + ch) * 64 + lane) * 4;
#pragma unroll
        for (int f = 0; f < 4; ++f) red[si + f] = acc[f];
    }
    __syncthreads();
    if (kh == 0) {
#pragma unroll
        for (int p = 0; p < 3; ++p) {
            int si = ((p * 2 + ch) * 64 + lane) * 4;
#pragma unroll
            for (int f = 0; f < 4; ++f) acc[f] += red[si + f];
        }
        if constexpr (!HASW) {
            int rbase = m0 + (lane >> 4) * 4;
            float4 d4 = *reinterpret_cast<const float4*>(&dinv[rbase]);
#pragma unroll
            for (int f = 0; f < 4; ++f) {
                int col = ch * 64 + f * 16 + lrow;
                float bv = bias[col];
                float v0 = fmaxf(acc[f][0] * d4.x + bv, 0.f);
                float v1 = fmaxf(acc[f][1] * d4.y + bv, 0.f);
                float v2 = fmaxf(acc[f][2] * d4.z + bv, 0.f);
                float v3 = fmaxf(acc[f][3] * d4.w + bv, 0.f);
                float* op = outp + (size_t)rbase * GH + col;
                if (MODE == 0) {
                    op[0] = 0.25f * v0; op[GH] = 0.25f * v1;
                    op[2 * GH] = 0.25f * v2; op[3 * GH] = 0.25f * v3;
                } else {
                    op[0] += 0.25f * v0; op[GH] += 0.25f * v1;
                    op[2 * GH] += 0.25f * v2; op[3 * GH] += 0.25f * v3;
                }
                if (MODE != 2) {
                    bf16x4 h4;
                    h4[0] = (bf16)(v0 * d4.x); h4[1] = (bf16)(v1 * d4.y);
                    h4[2] = (bf16)(v2 * d4.z); h4[3] = (bf16)(v3 * d4.w);
                    *reinterpret_cast<bf16x4*>(Hst + (size_t)col * MROWS + rbase) = h4;
                }
            }
        } else {
#pragma unroll
            for (int f = 0; f < 4; ++f) {
                int tcol = ch * 64 + f * 16 + lrow;
#pragma unroll
                for (int r = 0; r < 4; ++r) {
                    int trow = (lane >> 4) * 4 + r;
                    float tv = acc[f][r];
                    bf16 hi = (bf16)tv;
                    int ei = trow * 128 + (tcol ^ ((trow & 7) << 3));
                    Ths[ei] = hi;
                    Tls[ei] = (bf16)(tv - (float)hi);
                }
            }
        }
    }
    if constexpr (HASW) {
        __syncthreads();
        f32x4 u = {};
        int wcol = wave * 16 + lrow;
#pragma unroll
        for (int ks = 0; ks < 4; ++ks) {
            int e0 = ks * 32 + lk;
            int te = lrow * 128 + (e0 ^ ((lrow & 7) << 3));
            bf16x8 thi = *reinterpret_cast<const bf16x8*>(&Ths[te]);
            bf16x8 tlo = *reinterpret_cast<const bf16x8*>(&Tls[te]);
            bf16x8 wv = reinterpret_cast<const bf16x8*>(Wlds)[wcol * 16 + ((e0 >> 3) ^ (wcol & 7))];
            u = mfma16(thi, wv, u);
            u = mfma16(tlo, wv, u);
        }
        int r0 = (lane >> 4) * 4;
        float4 d4 = *reinterpret_cast<const float4*>(&dinv[m0 + r0]);
        float bv = bias[wcol];
        float v0 = fmaxf(u[0] * d4.x + bv, 0.f);
        float v1 = fmaxf(u[1] * d4.y + bv, 0.f);
        float v2 = fmaxf(u[2] * d4.z + bv, 0.f);
        float v3 = fmaxf(u[3] * d4.w + bv, 0.f);
        float* op = outp + (size_t)(m0 + r0) * GH + wcol;
        if (MODE == 0) {
            op[0] = 0.25f * v0; op[GH] = 0.25f * v1;
            op[2 * GH] = 0.25f * v2; op[3 * GH] = 0.25f * v3;
        } else {
            op[0] += 0.25f * v0; op[GH] += 0.25f * v1;
            op[2 * GH] += 0.25f * v2; op[3 * GH] += 0.25f * v3;
        }
        if (MODE != 2) {
            bf16x4 h4;
            h4[0] = (bf16)(v0 * d4.x); h4[1] = (bf16)(v1 * d4.y);
            h4[2] = (bf16)(v2 * d4.z); h4[3] = (bf16)(v3 * d4.w);
            *reinterpret_cast<bf16x4*>(Hst + (size_t)wcol * MROWS + m0 + r0) = h4;
        }
    }
}

extern "C" void kernel_launch(void* const* d_in, const int* in_sizes, int n_in,
                              void* d_out, int out_size, void* d_ws, size_t ws_size,
                              hipStream_t stream) {
    const float* aa    = (const float*)d_in[0];
    const int*   rpa   = (const int*)d_in[1];
    const float* W_in  = (const float*)d_in[2];
    const float* b_in  = (const float*)d_in[3];
    const float* W_h0  = (const float*)d_in[4];
    const float* b_h0  = (const float*)d_in[5];
    const float* W_h1  = (const float*)d_in[6];
    const float* b_h1  = (const float*)d_in[7];
    const float* W_out = (const float*)d_in[8];
    const float* b_out = (const float*)d_in[9];
    float* out = (float*)d_out;

    char* ws = (char*)d_ws;
    size_t off = 0;
    float* dinv = (float*)(ws + off); off += (size_t)MROWS * 4;
    bf16*  A01  = (bf16*)(ws + off);  off += (size_t)MROWS * NN * 2;
    bf16*  Xt   = (bf16*)(ws + off);  off += (size_t)GH * MROWS * 2;
    bf16*  HstA = (bf16*)(ws + off);  off += (size_t)GH * MROWS * 2;
    bf16*  HstB = (bf16*)(ws + off);  off += (size_t)GH * MROWS * 2;
    bf16*  Wt0  = (bf16*)(ws + off);  off += (size_t)GH * NN * 2;
    bf16*  Wt1  = (bf16*)(ws + off);  off += (size_t)GH * GH * 2;
    bf16*  Wt2  = (bf16*)(ws + off);  off += (size_t)GH * GH * 2;
    bf16*  Wt3  = (bf16*)(ws + off);  off += (size_t)GH * GH * 2;
    unsigned* bar = (unsigned*)(ws + off); off += 1024;

    hipMemsetAsync(bar, 0, 1024, stream);  // zero barrier counters/generation each launch

    void* args[] = {(void*)&rpa, (void*)&aa,
                    (void*)&W_in, (void*)&W_h0, (void*)&W_h1, (void*)&W_out,
                    (void*)&b_in, (void*)&b_h0, (void*)&b_h1, (void*)&b_out,
                    (void*)&A01, (void*)&dinv,
                    (void*)&Wt0, (void*)&Wt1, (void*)&Wt2, (void*)&Wt3,
                    (void*)&Xt, (void*)&HstA, (void*)&HstB, (void*)&out, (void*)&bar};
    hipError_t err = hipLaunchCooperativeKernel((void*)mega2_kernel, dim3(512), dim3(512),
                                                args, 0, stream);
    if (err != hipSuccess) {
        // deterministic fallback: round-5 pipeline (verified, ~126us)
        prep_wtrans_kernel<<<2136, 256, 0, stream>>>(rpa, W_in, W_h0, W_h1, W_out,
                                                     A01, dinv, Wt0, Wt1, Wt2, Wt3);
        gemm_kernel<NN, true><<<512, 512, 0, stream>>>(aa, Wt0, dinv, Xt);
        fused_kernel<0, false><<<512, 512, 0, stream>>>(A01, Xt,   Wt1, dinv, b_in,  HstA, out);
        fused_kernel<1, true><<<512, 512, 0, stream>>>(A01, HstA, Wt1, dinv, b_h0, HstB, out);
        fused_kernel<1, true><<<512, 512, 0, stream>>>(A01, HstB, Wt2, dinv, b_h1, HstA, out);
        fused_kernel<2, true><<<512, 512, 0, stream>>>(A01, HstA, Wt3, dinv, b_out, HstB, out);
    }
}

// Round 9
// 124.719 us; speedup vs baseline: 5.1575x; 5.1575x over previous
//
#include <hip/hip_runtime.h>
#include <hip/hip_bf16.h>

typedef __bf16 bf16;
typedef __bf16 bf16x4 __attribute__((ext_vector_type(4)));
typedef __bf16 bf16x8 __attribute__((ext_vector_type(8)));
typedef float f32x4 __attribute__((ext_vector_type(4)));

#define NN 1024
#define GH 128
#define MROWS 8192  // 8*1024

static __device__ __forceinline__ f32x4 mfma16(bf16x8 a, bf16x8 b, f32x4 c) {
    return __builtin_amdgcn_mfma_f32_16x16x32_bf16(a, b, c, 0, 0, 0);
}

// ---------------- prep (A01 + dinv) fused with weight transposes ----------------
// blocks 0..2047: prep 4 rows each, XCD-swizzled so rows of batch b are written on XCD b.
// blocks 2048..2135: Wt[n][k] = (bf16)W[k][n].
__global__ __launch_bounds__(256) void prep_wtrans_kernel(
        const int* __restrict__ rpa,
        const float* __restrict__ W0, const float* __restrict__ W1,
        const float* __restrict__ W2, const float* __restrict__ W3,
        bf16* __restrict__ A01, float* __restrict__ dinv,
        bf16* __restrict__ T0, bf16* __restrict__ T1,
        bf16* __restrict__ T2, bf16* __restrict__ T3) {
    int bid = blockIdx.x;
    if (bid < 2048) {
        // XCD swizzle: rb = (bid%8)*256 + bid/8  ->  batch(rb*4) = rb/256 = bid%8 = XCD(bid)
        int rb = (bid & 7) * 256 + (bid >> 3);
        int row  = rb * 4 + (threadIdx.x >> 6);
        int lane = threadIdx.x & 63;
        int i = row & (NN - 1);
        const int4* p = reinterpret_cast<const int4*>(rpa + (size_t)row * NN);
        bf16* arow = A01 + (size_t)row * NN;
        int cnt = 0;
#pragma unroll
        for (int it = 0; it < 4; ++it) {
            int4 v = p[lane + it * 64];
            int j = (lane + it * 64) * 4;
            int a0 = (v.x != 0), a1 = (v.y != 0), a2 = (v.z != 0), a3 = (v.w != 0);
            cnt += (a0 & (j + 0 != i)) + (a1 & (j + 1 != i)) +
                   (a2 & (j + 2 != i)) + (a3 & (j + 3 != i));
            bf16x4 o;
            o[0] = (bf16)((a0 | (j + 0 == i)) ? 1.f : 0.f);
            o[1] = (bf16)((a1 | (j + 1 == i)) ? 1.f : 0.f);
            o[2] = (bf16)((a2 | (j + 2 == i)) ? 1.f : 0.f);
            o[3] = (bf16)((a3 | (j + 3 == i)) ? 1.f : 0.f);
            *reinterpret_cast<bf16x4*>(arow + j) = o;
        }
#pragma unroll
        for (int off = 32; off > 0; off >>= 1) cnt += __shfl_down(cnt, off, 64);
        if (lane == 0) dinv[row] = rsqrtf((float)(cnt + 1));  // +1 self-loop
    } else {
        int t = (bid - 2048) * 256 + threadIdx.x;  // 0..22527
        const float* W; bf16* T; int K; int local;
        if (t < 16384)      { W = W0; T = T0; K = NN; local = t; }
        else if (t < 18432) { W = W1; T = T1; K = GH; local = t - 16384; }
        else if (t < 20480) { W = W2; T = T2; K = GH; local = t - 18432; }
        else                { W = W3; T = T3; K = GH; local = t - 20480; }
        int n = local & 127, k0 = (local >> 7) * 8;
        bf16x8 o;
#pragma unroll
        for (int ii = 0; ii < 8; ++ii) o[ii] = (bf16)W[(size_t)(k0 + ii) * GH + n];
        *reinterpret_cast<bf16x8*>(T + (size_t)n * K + k0) = o;
    }
}

// ---------------- GEMM: Xt[n][m] = bf16(dinv[m] * sum_k aa[m][k] * Wt[n][k]) ----------------
// tile 16 rows x 128 cols; 512 thr = 8 waves = 4 K-quarters x 2 col-halves; grid 512.
// XCD swizzle: Xt rows of batch b are produced on XCD b (consumed there by fused layers).
template <int K, bool AF32>
__global__ __launch_bounds__(512, 4) void gemm_kernel(const void* __restrict__ Av,
                                                      const bf16* __restrict__ Wt,
                                                      const float* __restrict__ dinv,
                                                      bf16* __restrict__ Zt) {
    __shared__ f32x4 red[1536];
    int wave = threadIdx.x >> 6, lane = threadIdx.x & 63;
    int kh = wave >> 1, ch = wave & 1;
    int lrow = lane & 15, lk = (lane >> 4) * 8;
    int lb = (blockIdx.x & 7) * 64 + (blockIdx.x >> 3);  // bijective, batch(lb)=bid%8=XCD
    int m0 = lb * 16;
    constexpr int KH = K / 4;
    int kb = kh * KH;
    const bf16* Bp = Wt + (size_t)(ch * 64 + lrow) * K + kb + lk;
    f32x4 acc[4] = {};
    if constexpr (AF32) {
        const float* Ap = (const float*)Av + (size_t)(m0 + lrow) * K + kb + lk;
#pragma unroll 2
        for (int k = 0; k < KH; k += 32) {
            float4 a0 = *reinterpret_cast<const float4*>(Ap + k);
            float4 a1 = *reinterpret_cast<const float4*>(Ap + k + 4);
            bf16x8 a;
            a[0] = (bf16)a0.x; a[1] = (bf16)a0.y; a[2] = (bf16)a0.z; a[3] = (bf16)a0.w;
            a[4] = (bf16)a1.x; a[5] = (bf16)a1.y; a[6] = (bf16)a1.z; a[7] = (bf16)a1.w;
#pragma unroll
            for (int f = 0; f < 4; ++f) {
                bf16x8 bb = *reinterpret_cast<const bf16x8*>(Bp + (size_t)f * 16 * K + k);
                acc[f] = mfma16(a, bb, acc[f]);
            }
        }
    } else {
        const bf16* Ap = (const bf16*)Av + (size_t)(m0 + lrow) * K + kb + lk;
#pragma unroll 4
        for (int k = 0; k < KH; k += 32) {
            bf16x8 a = *reinterpret_cast<const bf16x8*>(Ap + k);
#pragma unroll
            for (int f = 0; f < 4; ++f) {
                bf16x8 bb = *reinterpret_cast<const bf16x8*>(Bp + (size_t)f * 16 * K + k);
                acc[f] = mfma16(a, bb, acc[f]);
            }
        }
    }
    if (kh != 0) {
        int si = (((kh - 1) * 2 + ch) * 64 + lane) * 4;
#pragma unroll
        for (int f = 0; f < 4; ++f) red[si + f] = acc[f];
    }
    __syncthreads();
    if (kh == 0) {
#pragma unroll
        for (int p = 0; p < 3; ++p) {
            int si = ((p * 2 + ch) * 64 + lane) * 4;
#pragma unroll
            for (int f = 0; f < 4; ++f) acc[f] += red[si + f];
        }
        int rbase = m0 + (lane >> 4) * 4;
        float4 d4 = *reinterpret_cast<const float4*>(&dinv[rbase]);
#pragma unroll
        for (int f = 0; f < 4; ++f) {
            int col = ch * 64 + f * 16 + lrow;
            bf16x4 o;
            o[0] = (bf16)(acc[f][0] * d4.x);
            o[1] = (bf16)(acc[f][1] * d4.y);
            o[2] = (bf16)(acc[f][2] * d4.z);
            o[3] = (bf16)(acc[f][3] * d4.w);
            *reinterpret_cast<bf16x4*>(Zt + (size_t)col * MROWS + rbase) = o;
        }
    }
}

// ---------------- fused layer: T = A01_b @ Xt_b ; [U = T@W] ; v = relu(D*U + b) ----------------
// Xt layout [GH][MROWS] (= D*h transposed). HASW: epilogue U = T@W via hi/lo bf16 split MFMA.
// MODE: 0 out=0.25v (write Hst), 1 out+=0.25v (write Hst), 2 out+=0.25v (no Hst).
// XCD swizzle: batch = bid%8 = XCD -> A01/Xt/Hst/out slices stay in this XCD's L2 all 4 layers.
template <int MODE, bool HASW>
__global__ __launch_bounds__(512, 4) void fused_kernel(const bf16* __restrict__ A01,
                                                       const bf16* __restrict__ Xt,
                                                       const bf16* __restrict__ Wt,
                                                       const float* __restrict__ dinv,
                                                       const float* __restrict__ bias,
                                                       bf16* __restrict__ Hst,
                                                       float* __restrict__ outp) {
    __shared__ f32x4 red[1536];   // 24KB split-K reduce
    __shared__ bf16 Wlds[16384];  // 32KB  Wt[col][k], XOR-swizzled
    __shared__ bf16 Ths[2048];    // 4KB   T hi, XOR-swizzled
    __shared__ bf16 Tls[2048];    // 4KB   T lo
    int wave = threadIdx.x >> 6, lane = threadIdx.x & 63;
    int kh = wave >> 1, ch = wave & 1;
    int lrow = lane & 15, lk = (lane >> 4) * 8;
    int lb = (blockIdx.x & 7) * 64 + (blockIdx.x >> 3);
    int m0 = lb * 16;
    int b  = blockIdx.x & 7;  // == lb>>6
    if constexpr (HASW) {
        const bf16x8* src = reinterpret_cast<const bf16x8*>(Wt);
        bf16x8* dst = reinterpret_cast<bf16x8*>(Wlds);
#pragma unroll
        for (int i = 0; i < 4; ++i) {
            int idx = threadIdx.x * 4 + i;            // x8 units; row = idx>>4
            dst[idx ^ ((idx >> 4) & 7)] = src[idx];
        }
    }
    constexpr int KH = NN / 4;
    int kb = kh * KH;
    const bf16* Ap = A01 + (size_t)(m0 + lrow) * NN + kb + lk;
    const bf16* Bp = Xt + (size_t)(ch * 64 + lrow) * MROWS + b * NN + kb + lk;
    f32x4 acc[4] = {};
#pragma unroll 4
    for (int k = 0; k < KH; k += 32) {
        bf16x8 a = *reinterpret_cast<const bf16x8*>(Ap + k);
#pragma unroll
        for (int f = 0; f < 4; ++f) {
            bf16x8 bb = *reinterpret_cast<const bf16x8*>(Bp + (size_t)f * 16 * MROWS + k);
            acc[f] = mfma16(a, bb, acc[f]);
        }
    }
    if (kh != 0) {
        int si = (((kh - 1) * 2 + ch) * 64 + lane) * 4;
#pragma unroll
        for (int f = 0; f < 4; ++f) red[si + f] = acc[f];
    }
    __syncthreads();
    if (kh == 0) {
#pragma unroll
        for (int p = 0; p < 3; ++p) {
            int si = ((p * 2 + ch) * 64 + lane) * 4;
#pragma unroll
            for (int f = 0; f < 4; ++f) acc[f] += red[si + f];
        }
        if constexpr (!HASW) {
            int rbase = m0 + (lane >> 4) * 4;
            float4 d4 = *reinterpret_cast<const float4*>(&dinv[rbase]);
#pragma unroll
            for (int f = 0; f < 4; ++f) {
                int col = ch * 64 + f * 16 + lrow;
                float bv = bias[col];
                float v0 = fmaxf(acc[f][0] * d4.x + bv, 0.f);
                float v1 = fmaxf(acc[f][1] * d4.y + bv, 0.f);
                float v2 = fmaxf(acc[f][2] * d4.z + bv, 0.f);
                float v3 = fmaxf(acc[f][3] * d4.w + bv, 0.f);
                float* op = outp + (size_t)rbase * GH + col;
                if (MODE == 0) {
                    op[0] = 0.25f * v0; op[GH] = 0.25f * v1;
                    op[2 * GH] = 0.25f * v2; op[3 * GH] = 0.25f * v3;
                } else {
                    op[0] += 0.25f * v0; op[GH] += 0.25f * v1;
                    op[2 * GH] += 0.25f * v2; op[3 * GH] += 0.25f * v3;
                }
                if (MODE != 2) {
                    bf16x4 h4;
                    h4[0] = (bf16)(v0 * d4.x); h4[1] = (bf16)(v1 * d4.y);
                    h4[2] = (bf16)(v2 * d4.z); h4[3] = (bf16)(v3 * d4.w);
                    *reinterpret_cast<bf16x4*>(Hst + (size_t)col * MROWS + rbase) = h4;
                }
            }
        } else {
            // store T as hi+lo bf16 (T = hi + lo; preserves f32 accuracy through MFMA epilogue)
#pragma unroll
            for (int f = 0; f < 4; ++f) {
                int tcol = ch * 64 + f * 16 + lrow;
#pragma unroll
                for (int r = 0; r < 4; ++r) {
                    int trow = (lane >> 4) * 4 + r;
                    float tv = acc[f][r];
                    bf16 hi = (bf16)tv;
                    int ei = trow * 128 + (tcol ^ ((trow & 7) << 3));
                    Ths[ei] = hi;
                    Tls[ei] = (bf16)(tv - (float)hi);
                }
            }
        }
    }
    if constexpr (HASW) {
        __syncthreads();
        // epilogue: wave handles U cols wave*16..+15; K=128
        f32x4 u = {};
        int wcol = wave * 16 + lrow;
#pragma unroll
        for (int ks = 0; ks < 4; ++ks) {
            int e0 = ks * 32 + lk;
            int te = lrow * 128 + (e0 ^ ((lrow & 7) << 3));
            bf16x8 thi = *reinterpret_cast<const bf16x8*>(&Ths[te]);
            bf16x8 tlo = *reinterpret_cast<const bf16x8*>(&Tls[te]);
            bf16x8 wv = reinterpret_cast<const bf16x8*>(Wlds)[wcol * 16 + ((e0 >> 3) ^ (wcol & 7))];
            u = mfma16(thi, wv, u);
            u = mfma16(tlo, wv, u);
        }
        int r0 = (lane >> 4) * 4;
        float4 d4 = *reinterpret_cast<const float4*>(&dinv[m0 + r0]);
        float bv = bias[wcol];
        float v0 = fmaxf(u[0] * d4.x + bv, 0.f);
        float v1 = fmaxf(u[1] * d4.y + bv, 0.f);
        float v2 = fmaxf(u[2] * d4.z + bv, 0.f);
        float v3 = fmaxf(u[3] * d4.w + bv, 0.f);
        float* op = outp + (size_t)(m0 + r0) * GH + wcol;
        if (MODE == 0) {
            op[0] = 0.25f * v0; op[GH] = 0.25f * v1;
            op[2 * GH] = 0.25f * v2; op[3 * GH] = 0.25f * v3;
        } else {
            op[0] += 0.25f * v0; op[GH] += 0.25f * v1;
            op[2 * GH] += 0.25f * v2; op[3 * GH] += 0.25f * v3;
        }
        if (MODE != 2) {
            bf16x4 h4;
            h4[0] = (bf16)(v0 * d4.x); h4[1] = (bf16)(v1 * d4.y);
            h4[2] = (bf16)(v2 * d4.z); h4[3] = (bf16)(v3 * d4.w);
            *reinterpret_cast<bf16x4*>(Hst + (size_t)wcol * MROWS + m0 + r0) = h4;
        }
    }
}

extern "C" void kernel_launch(void* const* d_in, const int* in_sizes, int n_in,
                              void* d_out, int out_size, void* d_ws, size_t ws_size,
                              hipStream_t stream) {
    const float* aa    = (const float*)d_in[0];
    const int*   rpa   = (const int*)d_in[1];
    const float* W_in  = (const float*)d_in[2];
    const float* b_in  = (const float*)d_in[3];
    const float* W_h0  = (const float*)d_in[4];
    const float* b_h0  = (const float*)d_in[5];
    const float* W_h1  = (const float*)d_in[6];
    const float* b_h1  = (const float*)d_in[7];
    const float* W_out = (const float*)d_in[8];
    const float* b_out = (const float*)d_in[9];
    float* out = (float*)d_out;

    char* ws = (char*)d_ws;
    size_t off = 0;
    float* dinv = (float*)(ws + off); off += (size_t)MROWS * 4;        // 32KB
    bf16*  A01  = (bf16*)(ws + off);  off += (size_t)MROWS * NN * 2;   // 16MB
    bf16*  Xt   = (bf16*)(ws + off);  off += (size_t)GH * MROWS * 2;   // 2MB
    bf16*  HstA = (bf16*)(ws + off);  off += (size_t)GH * MROWS * 2;   // 2MB
    bf16*  HstB = (bf16*)(ws + off);  off += (size_t)GH * MROWS * 2;   // 2MB
    bf16*  Wt0  = (bf16*)(ws + off);  off += (size_t)GH * NN * 2;      // 256KB
    bf16*  Wt1  = (bf16*)(ws + off);  off += (size_t)GH * GH * 2;
    bf16*  Wt2  = (bf16*)(ws + off);  off += (size_t)GH * GH * 2;
    bf16*  Wt3  = (bf16*)(ws + off);  off += (size_t)GH * GH * 2;

    prep_wtrans_kernel<<<2136, 256, 0, stream>>>(rpa, W_in, W_h0, W_h1, W_out,
                                                 A01, dinv, Wt0, Wt1, Wt2, Wt3);
    gemm_kernel<NN, true><<<512, 512, 0, stream>>>(aa, Wt0, dinv, Xt);
    fused_kernel<0, false><<<512, 512, 0, stream>>>(A01, Xt,   Wt1, dinv, b_in,  HstA, out);
    fused_kernel<1, true><<<512, 512, 0, stream>>>(A01, HstA, Wt1, dinv, b_h0, HstB, out);
    fused_kernel<1, true><<<512, 512, 0, stream>>>(A01, HstB, Wt2, dinv, b_h1, HstA, out);
    fused_kernel<2, true><<<512, 512, 0, stream>>>(A01, HstA, Wt3, dinv, b_out, HstB, out);
}

// Round 11
// 112.785 us; speedup vs baseline: 5.7032x; 1.1058x over previous
//
#include <hip/hip_runtime.h>
#include <hip/hip_bf16.h>

typedef __bf16 bf16;
typedef __bf16 bf16x4 __attribute__((ext_vector_type(4)));
typedef __bf16 bf16x8 __attribute__((ext_vector_type(8)));
typedef float f32x4 __attribute__((ext_vector_type(4)));

#define NN 1024
#define GH 128
#define MROWS 8192  // 8*1024

static __device__ __forceinline__ f32x4 mfma16(bf16x8 a, bf16x8 b, f32x4 c) {
    return __builtin_amdgcn_mfma_f32_16x16x32_bf16(a, b, c, 0, 0, 0);
}

// ---------------- prep (A01 + dinv) fused with weight transposes (round-9, verified) ----------------
__global__ __launch_bounds__(256) void prep_wtrans_kernel(
        const int* __restrict__ rpa,
        const float* __restrict__ W0, const float* __restrict__ W1,
        const float* __restrict__ W2, const float* __restrict__ W3,
        bf16* __restrict__ A01, float* __restrict__ dinv,
        bf16* __restrict__ T0, bf16* __restrict__ T1,
        bf16* __restrict__ T2, bf16* __restrict__ T3) {
    int bid = blockIdx.x;
    if (bid < 2048) {
        int rb = (bid & 7) * 256 + (bid >> 3);  // XCD-local batch
        int row  = rb * 4 + (threadIdx.x >> 6);
        int lane = threadIdx.x & 63;
        int i = row & (NN - 1);
        const int4* p = reinterpret_cast<const int4*>(rpa + (size_t)row * NN);
        bf16* arow = A01 + (size_t)row * NN;
        int cnt = 0;
#pragma unroll
        for (int it = 0; it < 4; ++it) {
            int4 v = p[lane + it * 64];
            int j = (lane + it * 64) * 4;
            int a0 = (v.x != 0), a1 = (v.y != 0), a2 = (v.z != 0), a3 = (v.w != 0);
            cnt += (a0 & (j + 0 != i)) + (a1 & (j + 1 != i)) +
                   (a2 & (j + 2 != i)) + (a3 & (j + 3 != i));
            bf16x4 o;
            o[0] = (bf16)((a0 | (j + 0 == i)) ? 1.f : 0.f);
            o[1] = (bf16)((a1 | (j + 1 == i)) ? 1.f : 0.f);
            o[2] = (bf16)((a2 | (j + 2 == i)) ? 1.f : 0.f);
            o[3] = (bf16)((a3 | (j + 3 == i)) ? 1.f : 0.f);
            *reinterpret_cast<bf16x4*>(arow + j) = o;
        }
#pragma unroll
        for (int off = 32; off > 0; off >>= 1) cnt += __shfl_down(cnt, off, 64);
        if (lane == 0) dinv[row] = rsqrtf((float)(cnt + 1));  // +1 self-loop
    } else {
        int t = (bid - 2048) * 256 + threadIdx.x;  // 0..22527
        const float* W; bf16* T; int K; int local;
        if (t < 16384)      { W = W0; T = T0; K = NN; local = t; }
        else if (t < 18432) { W = W1; T = T1; K = GH; local = t - 16384; }
        else if (t < 20480) { W = W2; T = T2; K = GH; local = t - 18432; }
        else                { W = W3; T = T3; K = GH; local = t - 20480; }
        int n = local & 127, k0 = (local >> 7) * 8;
        bf16x8 o;
#pragma unroll
        for (int ii = 0; ii < 8; ++ii) o[ii] = (bf16)W[(size_t)(k0 + ii) * GH + n];
        *reinterpret_cast<bf16x8*>(T + (size_t)n * K + k0) = o;
    }
}

// ---------------- gemm2: Xt[n][m] = bf16(dinv[m] * sum_k aa[m][k] * Wt0[n][k]) ----------------
// 512 blocks x 512 thr; tile 16 rows x 128 cols; A (f32->bf16) staged in LDS (XOR-swizzled);
// each wave owns one col-16, full K=1024 as 2 interleaved 16-deep MFMA chains. No split-K.
__global__ __launch_bounds__(512, 4) void gemm2_kernel(const float* __restrict__ aa,
                                                       const bf16* __restrict__ Wt,
                                                       const float* __restrict__ dinv,
                                                       bf16* __restrict__ Zt) {
    __shared__ bf16 Alds[16384];  // [16 rows][128 units of 8]; unit u at u^(row&7)
    int tid = threadIdx.x;
    int wave = tid >> 6, lane = tid & 63;
    int lrow = lane & 15, lg = lane >> 4;
    int lb = (blockIdx.x & 7) * 64 + (blockIdx.x >> 3);
    int m0 = lb * 16;
#pragma unroll
    for (int i = 0; i < 4; ++i) {
        int idx = i * 512 + tid;          // wave-contiguous: whole wave in one row
        int row = idx >> 7, u = idx & 127;
        const float* src = aa + (size_t)(m0 + row) * NN + u * 8;
        float4 f0 = *reinterpret_cast<const float4*>(src);
        float4 f1 = *reinterpret_cast<const float4*>(src + 4);
        bf16x8 v;
        v[0] = (bf16)f0.x; v[1] = (bf16)f0.y; v[2] = (bf16)f0.z; v[3] = (bf16)f0.w;
        v[4] = (bf16)f1.x; v[5] = (bf16)f1.y; v[6] = (bf16)f1.z; v[7] = (bf16)f1.w;
        *reinterpret_cast<bf16x8*>(&Alds[(row * 128 + (u ^ (row & 7))) * 8]) = v;
    }
    __syncthreads();
    int c0 = wave * 16;
    const bf16* Bp = Wt + (size_t)(c0 + lrow) * NN + lg * 8;
    f32x4 acc0 = {}, acc1 = {};
#pragma unroll 8
    for (int ks = 0; ks < 16; ++ks) {
        int u0 = ks * 4 + lg;
        bf16x8 a0 = *reinterpret_cast<const bf16x8*>(&Alds[(lrow * 128 + (u0 ^ (lrow & 7))) * 8]);
        bf16x8 b0 = *reinterpret_cast<const bf16x8*>(Bp + ks * 32);
        acc0 = mfma16(a0, b0, acc0);
        int u1 = (ks + 16) * 4 + lg;
        bf16x8 a1 = *reinterpret_cast<const bf16x8*>(&Alds[(lrow * 128 + (u1 ^ (lrow & 7))) * 8]);
        bf16x8 b1 = *reinterpret_cast<const bf16x8*>(Bp + (ks + 16) * 32);
        acc1 = mfma16(a1, b1, acc1);
    }
    f32x4 acc = acc0 + acc1;
    int rl = lg * 4;
    int rbase = m0 + rl;
    float4 d4 = *reinterpret_cast<const float4*>(&dinv[rbase]);
    int col = c0 + lrow;
    bf16x4 o;
    o[0] = (bf16)(acc[0] * d4.x);
    o[1] = (bf16)(acc[1] * d4.y);
    o[2] = (bf16)(acc[2] * d4.z);
    o[3] = (bf16)(acc[3] * d4.w);
    *reinterpret_cast<bf16x4*>(Zt + (size_t)col * MROWS + rbase) = o;
}

// ---------------- fused2: T = A01_b @ Xt_b ; [U = T@W from global] ; v = relu(D*U + b) ----------------
// No-split-K structure; Ths/Tls in DEDICATED LDS (no alias with Alds -> no WAR hazard).
// MODE: 0 out=0.25v (write Hst), 1 out+=0.25v (write Hst), 2 out+=0.25v (no Hst).
template <int MODE, bool HASW>
__global__ __launch_bounds__(512, 4) void fused2_kernel(const bf16* __restrict__ A01,
                                                        const bf16* __restrict__ Xt,
                                                        const bf16* __restrict__ Wt,
                                                        const float* __restrict__ dinv,
                                                        const float* __restrict__ bias,
                                                        bf16* __restrict__ Hst,
                                                        float* __restrict__ outp) {
    __shared__ bf16 Alds[16384];  // 32KB A-tile
    __shared__ bf16 Ths[2048];    // 4KB  T hi (dedicated; NOT aliased)
    __shared__ bf16 Tls[2048];    // 4KB  T lo
    int tid = threadIdx.x;
    int wave = tid >> 6, lane = tid & 63;
    int lrow = lane & 15, lg = lane >> 4;
    int lb = (blockIdx.x & 7) * 64 + (blockIdx.x >> 3);
    int m0 = lb * 16;
    int b = blockIdx.x & 7;
#pragma unroll
    for (int i = 0; i < 4; ++i) {
        int idx = i * 512 + tid;
        int row = idx >> 7, u = idx & 127;
        bf16x8 v = *reinterpret_cast<const bf16x8*>(A01 + (size_t)(m0 + row) * NN + u * 8);
        *reinterpret_cast<bf16x8*>(&Alds[(row * 128 + (u ^ (row & 7))) * 8]) = v;
    }
    __syncthreads();
    int c0 = wave * 16;
    const bf16* Bp = Xt + (size_t)(c0 + lrow) * MROWS + b * NN + lg * 8;
    f32x4 acc0 = {}, acc1 = {};
#pragma unroll 8
    for (int ks = 0; ks < 16; ++ks) {
        int u0 = ks * 4 + lg;
        bf16x8 a0 = *reinterpret_cast<const bf16x8*>(&Alds[(lrow * 128 + (u0 ^ (lrow & 7))) * 8]);
        bf16x8 b0 = *reinterpret_cast<const bf16x8*>(Bp + ks * 32);
        acc0 = mfma16(a0, b0, acc0);
        int u1 = (ks + 16) * 4 + lg;
        bf16x8 a1 = *reinterpret_cast<const bf16x8*>(&Alds[(lrow * 128 + (u1 ^ (lrow & 7))) * 8]);
        bf16x8 b1 = *reinterpret_cast<const bf16x8*>(Bp + (ks + 16) * 32);
        acc1 = mfma16(a1, b1, acc1);
    }
    f32x4 acc = acc0 + acc1;
    int rl = lg * 4;

    if constexpr (!HASW) {
        // direct epilogue: every wave owns col-16; no further barriers
        int rbase = m0 + rl;
        float4 d4 = *reinterpret_cast<const float4*>(&dinv[rbase]);
        int col = c0 + lrow;
        float bv = bias[col];
        float v0 = fmaxf(acc[0] * d4.x + bv, 0.f);
        float v1 = fmaxf(acc[1] * d4.y + bv, 0.f);
        float v2 = fmaxf(acc[2] * d4.z + bv, 0.f);
        float v3 = fmaxf(acc[3] * d4.w + bv, 0.f);
        float* op = outp + (size_t)rbase * GH + col;
        if (MODE == 0) {
            op[0] = 0.25f * v0; op[GH] = 0.25f * v1;
            op[2 * GH] = 0.25f * v2; op[3 * GH] = 0.25f * v3;
        } else {
            op[0] += 0.25f * v0; op[GH] += 0.25f * v1;
            op[2 * GH] += 0.25f * v2; op[3 * GH] += 0.25f * v3;
        }
        if (MODE != 2) {
            bf16x4 h4;
            h4[0] = (bf16)(v0 * d4.x); h4[1] = (bf16)(v1 * d4.y);
            h4[2] = (bf16)(v2 * d4.z); h4[3] = (bf16)(v3 * d4.w);
            *reinterpret_cast<bf16x4*>(Hst + (size_t)col * MROWS + rbase) = h4;
        }
    } else {
        // T (16x128) -> dedicated LDS as hi+lo bf16
        __syncthreads();  // conservative: keep phase separation
        {
            int tcol = c0 + lrow;
#pragma unroll
            for (int r = 0; r < 4; ++r) {
                int trow = rl + r;
                float tv = acc[r];
                bf16 hi = (bf16)tv;
                int ei = trow * 128 + (tcol ^ ((trow & 7) << 3));
                Ths[ei] = hi;
                Tls[ei] = (bf16)(tv - (float)hi);
            }
        }
        __syncthreads();
        // U = T@W epilogue; wave handles U cols wave*16..+15; K=128; W from L2-resident global
        f32x4 u = {};
        int wcol = c0 + lrow;
#pragma unroll
        for (int ks = 0; ks < 4; ++ks) {
            int e0 = ks * 32 + lg * 8;
            int te = lrow * 128 + (e0 ^ ((lrow & 7) << 3));
            bf16x8 thi = *reinterpret_cast<const bf16x8*>(&Ths[te]);
            bf16x8 tlo = *reinterpret_cast<const bf16x8*>(&Tls[te]);
            bf16x8 wv = *reinterpret_cast<const bf16x8*>(Wt + (size_t)wcol * GH + e0);
            u = mfma16(thi, wv, u);
            u = mfma16(tlo, wv, u);
        }
        int rbase = m0 + rl;
        float4 d4 = *reinterpret_cast<const float4*>(&dinv[rbase]);
        float bv = bias[wcol];
        float v0 = fmaxf(u[0] * d4.x + bv, 0.f);
        float v1 = fmaxf(u[1] * d4.y + bv, 0.f);
        float v2 = fmaxf(u[2] * d4.z + bv, 0.f);
        float v3 = fmaxf(u[3] * d4.w + bv, 0.f);
        float* op = outp + (size_t)rbase * GH + wcol;
        if (MODE == 0) {
            op[0] = 0.25f * v0; op[GH] = 0.25f * v1;
            op[2 * GH] = 0.25f * v2; op[3 * GH] = 0.25f * v3;
        } else {
            op[0] += 0.25f * v0; op[GH] += 0.25f * v1;
            op[2 * GH] += 0.25f * v2; op[3 * GH] += 0.25f * v3;
        }
        if (MODE != 2) {
            bf16x4 h4;
            h4[0] = (bf16)(v0 * d4.x); h4[1] = (bf16)(v1 * d4.y);
            h4[2] = (bf16)(v2 * d4.z); h4[3] = (bf16)(v3 * d4.w);
            *reinterpret_cast<bf16x4*>(Hst + (size_t)wcol * MROWS + rbase) = h4;
        }
    }
}

extern "C" void kernel_launch(void* const* d_in, const int* in_sizes, int n_in,
                              void* d_out, int out_size, void* d_ws, size_t ws_size,
                              hipStream_t stream) {
    const float* aa    = (const float*)d_in[0];
    const int*   rpa   = (const int*)d_in[1];
    const float* W_in  = (const float*)d_in[2];
    const float* b_in  = (const float*)d_in[3];
    const float* W_h0  = (const float*)d_in[4];
    const float* b_h0  = (const float*)d_in[5];
    const float* W_h1  = (const float*)d_in[6];
    const float* b_h1  = (const float*)d_in[7];
    const float* W_out = (const float*)d_in[8];
    const float* b_out = (const float*)d_in[9];
    float* out = (float*)d_out;

    char* ws = (char*)d_ws;
    size_t off = 0;
    float* dinv = (float*)(ws + off); off += (size_t)MROWS * 4;        // 32KB
    bf16*  A01  = (bf16*)(ws + off);  off += (size_t)MROWS * NN * 2;   // 16MB
    bf16*  Xt   = (bf16*)(ws + off);  off += (size_t)GH * MROWS * 2;   // 2MB
    bf16*  HstA = (bf16*)(ws + off);  off += (size_t)GH * MROWS * 2;   // 2MB
    bf16*  HstB = (bf16*)(ws + off);  off += (size_t)GH * MROWS * 2;   // 2MB
    bf16*  Wt0  = (bf16*)(ws + off);  off += (size_t)GH * NN * 2;      // 256KB
    bf16*  Wt1  = (bf16*)(ws + off);  off += (size_t)GH * GH * 2;
    bf16*  Wt2  = (bf16*)(ws + off);  off += (size_t)GH * GH * 2;
    bf16*  Wt3  = (bf16*)(ws + off);  off += (size_t)GH * GH * 2;

    prep_wtrans_kernel<<<2136, 256, 0, stream>>>(rpa, W_in, W_h0, W_h1, W_out,
                                                 A01, dinv, Wt0, Wt1, Wt2, Wt3);
    gemm2_kernel<<<512, 512, 0, stream>>>(aa, Wt0, dinv, Xt);
    fused2_kernel<0, false><<<512, 512, 0, stream>>>(A01, Xt,   Wt1, dinv, b_in,  HstA, out);
    fused2_kernel<1, true><<<512, 512, 0, stream>>>(A01, HstA, Wt1, dinv, b_h0, HstB, out);
    fused2_kernel<1, true><<<512, 512, 0, stream>>>(A01, HstB, Wt2, dinv, b_h1, HstA, out);
    fused2_kernel<2, true><<<512, 512, 0, stream>>>(A01, HstA, Wt3, dinv, b_out, HstB, out);
}

// Round 12
// 112.370 us; speedup vs baseline: 5.7243x; 1.0037x over previous
//
#include <hip/hip_runtime.h>
#include <hip/hip_bf16.h>

typedef __bf16 bf16;
typedef __bf16 bf16x4 __attribute__((ext_vector_type(4)));
typedef __bf16 bf16x8 __attribute__((ext_vector_type(8)));
typedef float f32x4 __attribute__((ext_vector_type(4)));

#define NN 1024
#define GH 128
#define MROWS 8192  // 8*1024

static __device__ __forceinline__ f32x4 mfma16(bf16x8 a, bf16x8 b, f32x4 c) {
    return __builtin_amdgcn_mfma_f32_16x16x32_bf16(a, b, c, 0, 0, 0);
}

typedef __attribute__((address_space(1))) const unsigned int GUint;
typedef __attribute__((address_space(3))) unsigned int LUint;

// ---------------- prep: A01 (PRE-SWIZZLED 16B units: unit u stored at u^(row&7)) + dinv ----------------
// grid 2048; 4 rows/block (XCD-locked batches); wtrans folded in (11 units/block, threads 0..10).
__global__ __launch_bounds__(256) void prep_kernel(
        const int* __restrict__ rpa,
        const float* __restrict__ W0, const float* __restrict__ W1,
        const float* __restrict__ W2, const float* __restrict__ W3,
        bf16* __restrict__ A01, float* __restrict__ dinv,
        bf16* __restrict__ T0, bf16* __restrict__ T1,
        bf16* __restrict__ T2, bf16* __restrict__ T3) {
    int bid = blockIdx.x;
    {
        int rb = (bid & 7) * 256 + (bid >> 3);  // XCD-local batch
        int row  = rb * 4 + (threadIdx.x >> 6);
        int lane = threadIdx.x & 63;
        int i = row & (NN - 1);
        int rs = row & 7;
        const int4* p = reinterpret_cast<const int4*>(rpa + (size_t)row * NN);
        bf16* arow = A01 + (size_t)row * NN;
        int cnt = 0;
#pragma unroll
        for (int it = 0; it < 4; ++it) {
            int4 v = p[lane + it * 64];
            int j = (lane + it * 64) * 4;
            int a0 = (v.x != 0), a1 = (v.y != 0), a2 = (v.z != 0), a3 = (v.w != 0);
            cnt += (a0 & (j + 0 != i)) + (a1 & (j + 1 != i)) +
                   (a2 & (j + 2 != i)) + (a3 & (j + 3 != i));
            bf16x4 o;
            o[0] = (bf16)((a0 | (j + 0 == i)) ? 1.f : 0.f);
            o[1] = (bf16)((a1 | (j + 1 == i)) ? 1.f : 0.f);
            o[2] = (bf16)((a2 | (j + 2 == i)) ? 1.f : 0.f);
            o[3] = (bf16)((a3 | (j + 3 == i)) ? 1.f : 0.f);
            int su = (j >> 3) ^ rs;                      // swizzled 16B unit
            *reinterpret_cast<bf16x4*>(arow + su * 8 + (j & 4)) = o;
        }
#pragma unroll
        for (int off = 32; off > 0; off >>= 1) cnt += __shfl_down(cnt, off, 64);
        if (lane == 0) dinv[row] = rsqrtf((float)(cnt + 1));  // +1 self-loop
    }
    if (threadIdx.x < 11) {
        int t = bid * 11 + threadIdx.x;  // 0..22527 (2048*11 = 22528)
        const float* W; bf16* T; int K; int local;
        if (t < 16384)      { W = W0; T = T0; K = NN; local = t; }
        else if (t < 18432) { W = W1; T = T1; K = GH; local = t - 16384; }
        else if (t < 20480) { W = W2; T = T2; K = GH; local = t - 18432; }
        else                { W = W3; T = T3; K = GH; local = t - 20480; }
        int n = local & 127, k0 = (local >> 7) * 8;
        bf16x8 o;
#pragma unroll
        for (int ii = 0; ii < 8; ++ii) o[ii] = (bf16)W[(size_t)(k0 + ii) * GH + n];
        *reinterpret_cast<bf16x8*>(T + (size_t)n * K + k0) = o;
    }
}

// ---------------- gemm2: Xt[n][m] = bf16(dinv[m] * sum_k aa[m][k] * Wt0[n][k]) ----------------
// 512 blocks x 512 thr; 16x128 tile; A (f32->bf16) reg-staged into swizzled LDS; 4 acc chains.
__global__ __launch_bounds__(512, 4) void gemm2_kernel(const float* __restrict__ aa,
                                                       const bf16* __restrict__ Wt,
                                                       const float* __restrict__ dinv,
                                                       bf16* __restrict__ Zt) {
    __shared__ bf16 Alds[16384];  // [16 rows][128 units]; unit u at u^(row&7)
    int tid = threadIdx.x;
    int wave = tid >> 6, lane = tid & 63;
    int lrow = lane & 15, lg = lane >> 4;
    int lb = (blockIdx.x & 7) * 64 + (blockIdx.x >> 3);
    int m0 = lb * 16;
#pragma unroll
    for (int i = 0; i < 4; ++i) {
        int idx = i * 512 + tid;          // wave-contiguous: whole wave in one row
        int row = idx >> 7, u = idx & 127;
        const float* src = aa + (size_t)(m0 + row) * NN + u * 8;
        float4 f0 = *reinterpret_cast<const float4*>(src);
        float4 f1 = *reinterpret_cast<const float4*>(src + 4);
        bf16x8 v;
        v[0] = (bf16)f0.x; v[1] = (bf16)f0.y; v[2] = (bf16)f0.z; v[3] = (bf16)f0.w;
        v[4] = (bf16)f1.x; v[5] = (bf16)f1.y; v[6] = (bf16)f1.z; v[7] = (bf16)f1.w;
        *reinterpret_cast<bf16x8*>(&Alds[(row * 128 + (u ^ (row & 7))) * 8]) = v;
    }
    __syncthreads();
    int c0 = wave * 16;
    const bf16* Bp = Wt + (size_t)(c0 + lrow) * NN + lg * 8;
    f32x4 acc[4] = {};
#pragma unroll
    for (int f = 0; f < 32; ++f) {
        int u = f * 4 + lg;
        bf16x8 a = *reinterpret_cast<const bf16x8*>(&Alds[(lrow * 128 + (u ^ (lrow & 7))) * 8]);
        bf16x8 b = *reinterpret_cast<const bf16x8*>(Bp + f * 32);
        acc[f & 3] = mfma16(a, b, acc[f & 3]);
    }
    f32x4 s = (acc[0] + acc[1]) + (acc[2] + acc[3]);
    int rl = lg * 4;
    int rbase = m0 + rl;
    float4 d4 = *reinterpret_cast<const float4*>(&dinv[rbase]);
    int col = c0 + lrow;
    bf16x4 o;
    o[0] = (bf16)(s[0] * d4.x);
    o[1] = (bf16)(s[1] * d4.y);
    o[2] = (bf16)(s[2] * d4.z);
    o[3] = (bf16)(s[3] * d4.w);
    *reinterpret_cast<bf16x4*>(Zt + (size_t)col * MROWS + rbase) = o;
}

// ---------------- fused2: T = A01_b @ Xt_b ; [U = T@W from global] ; v = relu(D*U + b) ----------------
// A01 is pre-swizzled -> staging is pure global_load_lds (linear src, linear dest).
// Dedicated Ths/Tls (round-11 race lesson: never alias LDS across MFMA phases).
template <int MODE, bool HASW>
__global__ __launch_bounds__(512, 4) void fused2_kernel(const bf16* __restrict__ A01,
                                                        const bf16* __restrict__ Xt,
                                                        const bf16* __restrict__ Wt,
                                                        const float* __restrict__ dinv,
                                                        const float* __restrict__ bias,
                                                        bf16* __restrict__ Hst,
                                                        float* __restrict__ outp) {
    __shared__ bf16 Alds[16384];  // 32KB A-tile (swizzled content, loaded linearly)
    __shared__ bf16 Ths[2048];    // 4KB  T hi (dedicated)
    __shared__ bf16 Tls[2048];    // 4KB  T lo
    int tid = threadIdx.x;
    int wave = tid >> 6, lane = tid & 63;
    int lrow = lane & 15, lg = lane >> 4;
    int lb = (blockIdx.x & 7) * 64 + (blockIdx.x >> 3);
    int m0 = lb * 16;
    int b = blockIdx.x & 7;
    const bf16* Asrc = A01 + (size_t)m0 * NN;
#pragma unroll
    for (int i = 0; i < 4; ++i) {
        int idx = i * 512 + tid;  // 16B-unit index; per-wave: uniform base + lane*16
        __builtin_amdgcn_global_load_lds((GUint*)(Asrc + idx * 8),
                                         (LUint*)(Alds + idx * 8), 16, 0, 0);
    }
    __syncthreads();
    int c0 = wave * 16;
    const bf16* Bp = Xt + (size_t)(c0 + lrow) * MROWS + b * NN + lg * 8;
    f32x4 acc[4] = {};
#pragma unroll
    for (int f = 0; f < 32; ++f) {
        int u = f * 4 + lg;
        bf16x8 a = *reinterpret_cast<const bf16x8*>(&Alds[(lrow * 128 + (u ^ (lrow & 7))) * 8]);
        bf16x8 bb = *reinterpret_cast<const bf16x8*>(Bp + f * 32);
        acc[f & 3] = mfma16(a, bb, acc[f & 3]);
    }
    f32x4 s = (acc[0] + acc[1]) + (acc[2] + acc[3]);
    int rl = lg * 4;

    if constexpr (!HASW) {
        int rbase = m0 + rl;
        float4 d4 = *reinterpret_cast<const float4*>(&dinv[rbase]);
        int col = c0 + lrow;
        float bv = bias[col];
        float v0 = fmaxf(s[0] * d4.x + bv, 0.f);
        float v1 = fmaxf(s[1] * d4.y + bv, 0.f);
        float v2 = fmaxf(s[2] * d4.z + bv, 0.f);
        float v3 = fmaxf(s[3] * d4.w + bv, 0.f);
        float* op = outp + (size_t)rbase * GH + col;
        if (MODE == 0) {
            op[0] = 0.25f * v0; op[GH] = 0.25f * v1;
            op[2 * GH] = 0.25f * v2; op[3 * GH] = 0.25f * v3;
        } else {
            op[0] += 0.25f * v0; op[GH] += 0.25f * v1;
            op[2 * GH] += 0.25f * v2; op[3 * GH] += 0.25f * v3;
        }
        if (MODE != 2) {
            bf16x4 h4;
            h4[0] = (bf16)(v0 * d4.x); h4[1] = (bf16)(v1 * d4.y);
            h4[2] = (bf16)(v2 * d4.z); h4[3] = (bf16)(v3 * d4.w);
            *reinterpret_cast<bf16x4*>(Hst + (size_t)col * MROWS + rbase) = h4;
        }
    } else {
        // T (16x128) -> dedicated LDS as hi+lo bf16 (f32 accuracy through MFMA epilogue)
        __syncthreads();
        {
            int tcol = c0 + lrow;
#pragma unroll
            for (int r = 0; r < 4; ++r) {
                int trow = rl + r;
                float tv = s[r];
                bf16 hi = (bf16)tv;
                int ei = trow * 128 + (tcol ^ ((trow & 7) << 3));
                Ths[ei] = hi;
                Tls[ei] = (bf16)(tv - (float)hi);
            }
        }
        __syncthreads();
        // U = T@W; wave owns U cols wave*16..+15; K=128; W from L2-resident global
        f32x4 u = {};
        int wcol = c0 + lrow;
#pragma unroll
        for (int ks = 0; ks < 4; ++ks) {
            int e0 = ks * 32 + lg * 8;
            int te = lrow * 128 + (e0 ^ ((lrow & 7) << 3));
            bf16x8 thi = *reinterpret_cast<const bf16x8*>(&Ths[te]);
            bf16x8 tlo = *reinterpret_cast<const bf16x8*>(&Tls[te]);
            bf16x8 wv = *reinterpret_cast<const bf16x8*>(Wt + (size_t)wcol * GH + e0);
            u = mfma16(thi, wv, u);
            u = mfma16(tlo, wv, u);
        }
        int rbase = m0 + rl;
        float4 d4 = *reinterpret_cast<const float4*>(&dinv[rbase]);
        float bv = bias[wcol];
        float v0 = fmaxf(u[0] * d4.x + bv, 0.f);
        float v1 = fmaxf(u[1] * d4.y + bv, 0.f);
        float v2 = fmaxf(u[2] * d4.z + bv, 0.f);
        float v3 = fmaxf(u[3] * d4.w + bv, 0.f);
        float* op = outp + (size_t)rbase * GH + wcol;
        if (MODE == 0) {
            op[0] = 0.25f * v0; op[GH] = 0.25f * v1;
            op[2 * GH] = 0.25f * v2; op[3 * GH] = 0.25f * v3;
        } else {
            op[0] += 0.25f * v0; op[GH] += 0.25f * v1;
            op[2 * GH] += 0.25f * v2; op[3 * GH] += 0.25f * v3;
        }
        if (MODE != 2) {
            bf16x4 h4;
            h4[0] = (bf16)(v0 * d4.x); h4[1] = (bf16)(v1 * d4.y);
            h4[2] = (bf16)(v2 * d4.z); h4[3] = (bf16)(v3 * d4.w);
            *reinterpret_cast<bf16x4*>(Hst + (size_t)wcol * MROWS + rbase) = h4;
        }
    }
}

extern "C" void kernel_launch(void* const* d_in, const int* in_sizes, int n_in,
                              void* d_out, int out_size, void* d_ws, size_t ws_size,
                              hipStream_t stream) {
    const float* aa    = (const float*)d_in[0];
    const int*   rpa   = (const int*)d_in[1];
    const float* W_in  = (const float*)d_in[2];
    const float* b_in  = (const float*)d_in[3];
    const float* W_h0  = (const float*)d_in[4];
    const float* b_h0  = (const float*)d_in[5];
    const float* W_h1  = (const float*)d_in[6];
    const float* b_h1  = (const float*)d_in[7];
    const float* W_out = (const float*)d_in[8];
    const float* b_out = (const float*)d_in[9];
    float* out = (float*)d_out;

    char* ws = (char*)d_ws;
    size_t off = 0;
    float* dinv = (float*)(ws + off); off += (size_t)MROWS * 4;        // 32KB
    bf16*  A01  = (bf16*)(ws + off);  off += (size_t)MROWS * NN * 2;   // 16MB (pre-swizzled)
    bf16*  Xt   = (bf16*)(ws + off);  off += (size_t)GH * MROWS * 2;   // 2MB
    bf16*  HstA = (bf16*)(ws + off);  off += (size_t)GH * MROWS * 2;   // 2MB
    bf16*  HstB = (bf16*)(ws + off);  off += (size_t)GH * MROWS * 2;   // 2MB
    bf16*  Wt0  = (bf16*)(ws + off);  off += (size_t)GH * NN * 2;      // 256KB
    bf16*  Wt1  = (bf16*)(ws + off);  off += (size_t)GH * GH * 2;
    bf16*  Wt2  = (bf16*)(ws + off);  off += (size_t)GH * GH * 2;
    bf16*  Wt3  = (bf16*)(ws + off);  off += (size_t)GH * GH * 2;

    prep_kernel<<<2048, 256, 0, stream>>>(rpa, W_in, W_h0, W_h1, W_out,
                                          A01, dinv, Wt0, Wt1, Wt2, Wt3);
    gemm2_kernel<<<512, 512, 0, stream>>>(aa, Wt0, dinv, Xt);
    fused2_kernel<0, false><<<512, 512, 0, stream>>>(A01, Xt,   Wt1, dinv, b_in,  HstA, out);
    fused2_kernel<1, true><<<512, 512, 0, stream>>>(A01, HstA, Wt1, dinv, b_h0, HstB, out);
    fused2_kernel<1, true><<<512, 512, 0, stream>>>(A01, HstB, Wt2, dinv, b_h1, HstA, out);
    fused2_kernel<2, true><<<512, 512, 0, stream>>>(A01, HstA, Wt3, dinv, b_out, HstB, out);
}

// Round 13
// 109.917 us; speedup vs baseline: 5.8520x; 1.0223x over previous
//
#include <hip/hip_runtime.h>
#include <hip/hip_bf16.h>

typedef __bf16 bf16;
typedef __bf16 bf16x4 __attribute__((ext_vector_type(4)));
typedef __bf16 bf16x8 __attribute__((ext_vector_type(8)));
typedef float f32x4 __attribute__((ext_vector_type(4)));

#define NN 1024
#define GH 128
#define MROWS 8192  // 8*1024

static __device__ __forceinline__ f32x4 mfma16(bf16x8 a, bf16x8 b, f32x4 c) {
    return __builtin_amdgcn_mfma_f32_16x16x32_bf16(a, b, c, 0, 0, 0);
}

// ---------------- prep: A as 1-bit mask (diag=1) + dinv; wtrans folded (11 units/block) ----------------
// grid 2048; 4 rows/block (XCD-locked batches). Bits[row][128 bytes], bit c of byte u = col u*8+c.
__global__ __launch_bounds__(256) void prep_kernel(
        const int* __restrict__ rpa,
        const float* __restrict__ W0, const float* __restrict__ W1,
        const float* __restrict__ W2, const float* __restrict__ W3,
        unsigned char* __restrict__ A01b, float* __restrict__ dinv,
        bf16* __restrict__ T0, bf16* __restrict__ T1,
        bf16* __restrict__ T2, bf16* __restrict__ T3) {
    int bid = blockIdx.x;
    {
        int rb = (bid & 7) * 256 + (bid >> 3);  // XCD-local batch
        int row  = rb * 4 + (threadIdx.x >> 6);
        int lane = threadIdx.x & 63;
        int i = row & (NN - 1);
        const int4* p = reinterpret_cast<const int4*>(rpa + (size_t)row * NN);
        unsigned char* brow = A01b + (size_t)row * 128;
        int cnt = 0;
#pragma unroll
        for (int it = 0; it < 4; ++it) {
            int4 v = p[lane + it * 64];
            int j = (lane + it * 64) * 4;
            int a0 = (v.x != 0), a1 = (v.y != 0), a2 = (v.z != 0), a3 = (v.w != 0);
            cnt += (a0 & (j + 0 != i)) + (a1 & (j + 1 != i)) +
                   (a2 & (j + 2 != i)) + (a3 & (j + 3 != i));
            unsigned nib = (unsigned)(a0 | (j + 0 == i))
                         | ((unsigned)(a1 | (j + 1 == i)) << 1)
                         | ((unsigned)(a2 | (j + 2 == i)) << 2)
                         | ((unsigned)(a3 | (j + 3 == i)) << 3);
            unsigned pn = __shfl_xor(nib, 1, 64);     // partner lane's nibble
            if (!(lane & 1))                          // lane 2k: cols 8k..8k+3 low, 8k+4..7 high
                brow[it * 32 + (lane >> 1)] = (unsigned char)(nib | (pn << 4));
        }
#pragma unroll
        for (int off = 32; off > 0; off >>= 1) cnt += __shfl_down(cnt, off, 64);
        if (lane == 0) dinv[row] = rsqrtf((float)(cnt + 1));  // +1 self-loop
    }
    if (threadIdx.x < 11) {
        int t = bid * 11 + threadIdx.x;  // 0..22527 (2048*11 = 22528)
        const float* W; bf16* T; int K; int local;
        if (t < 16384)      { W = W0; T = T0; K = NN; local = t; }
        else if (t < 18432) { W = W1; T = T1; K = GH; local = t - 16384; }
        else if (t < 20480) { W = W2; T = T2; K = GH; local = t - 18432; }
        else                { W = W3; T = T3; K = GH; local = t - 20480; }
        int n = local & 127, k0 = (local >> 7) * 8;
        bf16x8 o;
#pragma unroll
        for (int ii = 0; ii < 8; ++ii) o[ii] = (bf16)W[(size_t)(k0 + ii) * GH + n];
        *reinterpret_cast<bf16x8*>(T + (size_t)n * K + k0) = o;
    }
}

// ---------------- gemm2: Xt[n][m] = bf16(dinv[m] * sum_k aa[m][k] * Wt0[n][k]) ----------------
// 512 blocks x 512 thr; 16x128 tile; A (f32->bf16) reg-staged into swizzled LDS; 4 acc chains.
__global__ __launch_bounds__(512, 4) void gemm2_kernel(const float* __restrict__ aa,
                                                       const bf16* __restrict__ Wt,
                                                       const float* __restrict__ dinv,
                                                       bf16* __restrict__ Zt) {
    __shared__ bf16 Alds[16384];  // [16 rows][128 units]; unit u at u^(row&7)
    int tid = threadIdx.x;
    int wave = tid >> 6, lane = tid & 63;
    int lrow = lane & 15, lg = lane >> 4;
    int lb = (blockIdx.x & 7) * 64 + (blockIdx.x >> 3);
    int m0 = lb * 16;
#pragma unroll
    for (int i = 0; i < 4; ++i) {
        int idx = i * 512 + tid;          // wave-contiguous: whole wave in one row
        int row = idx >> 7, u = idx & 127;
        const float* src = aa + (size_t)(m0 + row) * NN + u * 8;
        float4 f0 = *reinterpret_cast<const float4*>(src);
        float4 f1 = *reinterpret_cast<const float4*>(src + 4);
        bf16x8 v;
        v[0] = (bf16)f0.x; v[1] = (bf16)f0.y; v[2] = (bf16)f0.z; v[3] = (bf16)f0.w;
        v[4] = (bf16)f1.x; v[5] = (bf16)f1.y; v[6] = (bf16)f1.z; v[7] = (bf16)f1.w;
        *reinterpret_cast<bf16x8*>(&Alds[(row * 128 + (u ^ (row & 7))) * 8]) = v;
    }
    __syncthreads();
    int c0 = wave * 16;
    const bf16* Bp = Wt + (size_t)(c0 + lrow) * NN + lg * 8;
    f32x4 acc[4] = {};
#pragma unroll
    for (int f = 0; f < 32; ++f) {
        int u = f * 4 + lg;
        bf16x8 a = *reinterpret_cast<const bf16x8*>(&Alds[(lrow * 128 + (u ^ (lrow & 7))) * 8]);
        bf16x8 b = *reinterpret_cast<const bf16x8*>(Bp + f * 32);
        acc[f & 3] = mfma16(a, b, acc[f & 3]);
    }
    f32x4 s = (acc[0] + acc[1]) + (acc[2] + acc[3]);
    int rl = lg * 4;
    int rbase = m0 + rl;
    float4 d4 = *reinterpret_cast<const float4*>(&dinv[rbase]);
    int col = c0 + lrow;
    bf16x4 o;
    o[0] = (bf16)(s[0] * d4.x);
    o[1] = (bf16)(s[1] * d4.y);
    o[2] = (bf16)(s[2] * d4.z);
    o[3] = (bf16)(s[3] * d4.w);
    *reinterpret_cast<bf16x4*>(Zt + (size_t)col * MROWS + rbase) = o;
}

// ---------------- fused2: T = A01_b @ Xt_b ; [U = T@W from global] ; v = relu(D*U + b) ----------------
// A-tile expanded from the 1-bit mask into swizzled LDS (2KB bits -> 32KB bf16 per block).
// Dedicated Ths/Tls (round-11 race lesson: never alias LDS across MFMA phases).
template <int MODE, bool HASW>
__global__ __launch_bounds__(512, 4) void fused2_kernel(const unsigned char* __restrict__ A01b,
                                                        const bf16* __restrict__ Xt,
                                                        const bf16* __restrict__ Wt,
                                                        const float* __restrict__ dinv,
                                                        const float* __restrict__ bias,
                                                        bf16* __restrict__ Hst,
                                                        float* __restrict__ outp) {
    __shared__ bf16 Alds[16384];  // 32KB A-tile (swizzled: unit u of row r at u^(r&7))
    __shared__ bf16 Ths[2048];    // 4KB  T hi (dedicated)
    __shared__ bf16 Tls[2048];    // 4KB  T lo
    int tid = threadIdx.x;
    int wave = tid >> 6, lane = tid & 63;
    int lrow = lane & 15, lg = lane >> 4;
    int lb = (blockIdx.x & 7) * 64 + (blockIdx.x >> 3);
    int m0 = lb * 16;
    int b = blockIdx.x & 7;
    {
        // expand bits -> bf16 LDS: thread handles 4 units (one u32 of bits)
        int li = tid * 4;
        int row = li >> 7, ub = li & 127;
        unsigned w = *reinterpret_cast<const unsigned*>(A01b + (size_t)(m0 + row) * 128 + ub);
        int rs = row & 7;
#pragma unroll
        for (int i = 0; i < 4; ++i) {
            unsigned byte = (w >> (8 * i)) & 0xffu;
            bf16x8 v;
#pragma unroll
            for (int k = 0; k < 8; ++k) v[k] = ((byte >> k) & 1u) ? (bf16)1.f : (bf16)0.f;
            *reinterpret_cast<bf16x8*>(&Alds[(row * 128 + ((ub + i) ^ rs)) * 8]) = v;
        }
    }
    __syncthreads();
    int c0 = wave * 16;
    const bf16* Bp = Xt + (size_t)(c0 + lrow) * MROWS + b * NN + lg * 8;
    f32x4 acc[4] = {};
#pragma unroll
    for (int f = 0; f < 32; ++f) {
        int u = f * 4 + lg;
        bf16x8 a = *reinterpret_cast<const bf16x8*>(&Alds[(lrow * 128 + (u ^ (lrow & 7))) * 8]);
        bf16x8 bb = *reinterpret_cast<const bf16x8*>(Bp + f * 32);
        acc[f & 3] = mfma16(a, bb, acc[f & 3]);
    }
    f32x4 s = (acc[0] + acc[1]) + (acc[2] + acc[3]);
    int rl = lg * 4;

    if constexpr (!HASW) {
        int rbase = m0 + rl;
        float4 d4 = *reinterpret_cast<const float4*>(&dinv[rbase]);
        int col = c0 + lrow;
        float bv = bias[col];
        float v0 = fmaxf(s[0] * d4.x + bv, 0.f);
        float v1 = fmaxf(s[1] * d4.y + bv, 0.f);
        float v2 = fmaxf(s[2] * d4.z + bv, 0.f);
        float v3 = fmaxf(s[3] * d4.w + bv, 0.f);
        float* op = outp + (size_t)rbase * GH + col;
        if (MODE == 0) {
            op[0] = 0.25f * v0; op[GH] = 0.25f * v1;
            op[2 * GH] = 0.25f * v2; op[3 * GH] = 0.25f * v3;
        } else {
            op[0] += 0.25f * v0; op[GH] += 0.25f * v1;
            op[2 * GH] += 0.25f * v2; op[3 * GH] += 0.25f * v3;
        }
        if (MODE != 2) {
            bf16x4 h4;
            h4[0] = (bf16)(v0 * d4.x); h4[1] = (bf16)(v1 * d4.y);
            h4[2] = (bf16)(v2 * d4.z); h4[3] = (bf16)(v3 * d4.w);
            *reinterpret_cast<bf16x4*>(Hst + (size_t)col * MROWS + rbase) = h4;
        }
    } else {
        // T (16x128) -> dedicated LDS as hi+lo bf16 (f32 accuracy through MFMA epilogue)
        __syncthreads();
        {
            int tcol = c0 + lrow;
#pragma unroll
            for (int r = 0; r < 4; ++r) {
                int trow = rl + r;
                float tv = s[r];
                bf16 hi = (bf16)tv;
                int ei = trow * 128 + (tcol ^ ((trow & 7) << 3));
                Ths[ei] = hi;
                Tls[ei] = (bf16)(tv - (float)hi);
            }
        }
        __syncthreads();
        // U = T@W; wave owns U cols wave*16..+15; K=128; W from L2-resident global
        f32x4 u = {};
        int wcol = c0 + lrow;
#pragma unroll
        for (int ks = 0; ks < 4; ++ks) {
            int e0 = ks * 32 + lg * 8;
            int te = lrow * 128 + (e0 ^ ((lrow & 7) << 3));
            bf16x8 thi = *reinterpret_cast<const bf16x8*>(&Ths[te]);
            bf16x8 tlo = *reinterpret_cast<const bf16x8*>(&Tls[te]);
            bf16x8 wv = *reinterpret_cast<const bf16x8*>(Wt + (size_t)wcol * GH + e0);
            u = mfma16(thi, wv, u);
            u = mfma16(tlo, wv, u);
        }
        int rbase = m0 + rl;
        float4 d4 = *reinterpret_cast<const float4*>(&dinv[rbase]);
        float bv = bias[wcol];
        float v0 = fmaxf(u[0] * d4.x + bv, 0.f);
        float v1 = fmaxf(u[1] * d4.y + bv, 0.f);
        float v2 = fmaxf(u[2] * d4.z + bv, 0.f);
        float v3 = fmaxf(u[3] * d4.w + bv, 0.f);
        float* op = outp + (size_t)rbase * GH + wcol;
        if (MODE == 0) {
            op[0] = 0.25f * v0; op[GH] = 0.25f * v1;
            op[2 * GH] = 0.25f * v2; op[3 * GH] = 0.25f * v3;
        } else {
            op[0] += 0.25f * v0; op[GH] += 0.25f * v1;
            op[2 * GH] += 0.25f * v2; op[3 * GH] += 0.25f * v3;
        }
        if (MODE != 2) {
            bf16x4 h4;
            h4[0] = (bf16)(v0 * d4.x); h4[1] = (bf16)(v1 * d4.y);
            h4[2] = (bf16)(v2 * d4.z); h4[3] = (bf16)(v3 * d4.w);
            *reinterpret_cast<bf16x4*>(Hst + (size_t)wcol * MROWS + rbase) = h4;
        }
    }
}

extern "C" void kernel_launch(void* const* d_in, const int* in_sizes, int n_in,
                              void* d_out, int out_size, void* d_ws, size_t ws_size,
                              hipStream_t stream) {
    const float* aa    = (const float*)d_in[0];
    const int*   rpa   = (const int*)d_in[1];
    const float* W_in  = (const float*)d_in[2];
    const float* b_in  = (const float*)d_in[3];
    const float* W_h0  = (const float*)d_in[4];
    const float* b_h0  = (const float*)d_in[5];
    const float* W_h1  = (const float*)d_in[6];
    const float* b_h1  = (const float*)d_in[7];
    const float* W_out = (const float*)d_in[8];
    const float* b_out = (const float*)d_in[9];
    float* out = (float*)d_out;

    char* ws = (char*)d_ws;
    size_t off = 0;
    float* dinv = (float*)(ws + off); off += (size_t)MROWS * 4;            // 32KB
    unsigned char* A01b = (unsigned char*)(ws + off); off += (size_t)MROWS * 128;  // 1MB bitmask
    bf16*  Xt   = (bf16*)(ws + off);  off += (size_t)GH * MROWS * 2;       // 2MB
    bf16*  HstA = (bf16*)(ws + off);  off += (size_t)GH * MROWS * 2;       // 2MB
    bf16*  HstB = (bf16*)(ws + off);  off += (size_t)GH * MROWS * 2;       // 2MB
    bf16*  Wt0  = (bf16*)(ws + off);  off += (size_t)GH * NN * 2;          // 256KB
    bf16*  Wt1  = (bf16*)(ws + off);  off += (size_t)GH * GH * 2;
    bf16*  Wt2  = (bf16*)(ws + off);  off += (size_t)GH * GH * 2;
    bf16*  Wt3  = (bf16*)(ws + off);  off += (size_t)GH * GH * 2;

    prep_kernel<<<2048, 256, 0, stream>>>(rpa, W_in, W_h0, W_h1, W_out,
                                          A01b, dinv, Wt0, Wt1, Wt2, Wt3);
    gemm2_kernel<<<512, 512, 0, stream>>>(aa, Wt0, dinv, Xt);
    fused2_kernel<0, false><<<512, 512, 0, stream>>>(A01b, Xt,   Wt1, dinv, b_in,  HstA, out);
    fused2_kernel<1, true><<<512, 512, 0, stream>>>(A01b, HstA, Wt1, dinv, b_h0, HstB, out);
    fused2_kernel<1, true><<<512, 512, 0, stream>>>(A01b, HstB, Wt2, dinv, b_h1, HstA, out);
    fused2_kernel<2, true><<<512, 512, 0, stream>>>(A01b, HstA, Wt3, dinv, b_out, HstB, out);
}

// Round 14
// 75.606 us; speedup vs baseline: 8.5077x; 1.4538x over previous
//
#include <hip/hip_runtime.h>
#include <hip/hip_bf16.h>

typedef __bf16 bf16;
typedef __bf16 bf16x4 __attribute__((ext_vector_type(4)));
typedef __bf16 bf16x8 __attribute__((ext_vector_type(8)));
typedef float f32x4 __attribute__((ext_vector_type(4)));

#define NN 1024
#define GH 128
#define MROWS 8192  // 8*1024

static __device__ __forceinline__ f32x4 mfma16(bf16x8 a, bf16x8 b, f32x4 c) {
    return __builtin_amdgcn_mfma_f32_16x16x32_bf16(a, b, c, 0, 0, 0);
}

// ---------------- prep: A as 1-bit mask (diag=1) + dinv; wtrans folded (R13, verified) ----------------
__global__ __launch_bounds__(256) void prep_kernel(
        const int* __restrict__ rpa,
        const float* __restrict__ W0, const float* __restrict__ W1,
        const float* __restrict__ W2, const float* __restrict__ W3,
        unsigned char* __restrict__ A01b, float* __restrict__ dinv,
        bf16* __restrict__ T0, bf16* __restrict__ T1,
        bf16* __restrict__ T2, bf16* __restrict__ T3) {
    int bid = blockIdx.x;
    {
        int rb = (bid & 7) * 256 + (bid >> 3);  // XCD-local batch
        int row  = rb * 4 + (threadIdx.x >> 6);
        int lane = threadIdx.x & 63;
        int i = row & (NN - 1);
        const int4* p = reinterpret_cast<const int4*>(rpa + (size_t)row * NN);
        unsigned char* brow = A01b + (size_t)row * 128;
        int cnt = 0;
#pragma unroll
        for (int it = 0; it < 4; ++it) {
            int4 v = p[lane + it * 64];
            int j = (lane + it * 64) * 4;
            int a0 = (v.x != 0), a1 = (v.y != 0), a2 = (v.z != 0), a3 = (v.w != 0);
            cnt += (a0 & (j + 0 != i)) + (a1 & (j + 1 != i)) +
                   (a2 & (j + 2 != i)) + (a3 & (j + 3 != i));
            unsigned nib = (unsigned)(a0 | (j + 0 == i))
                         | ((unsigned)(a1 | (j + 1 == i)) << 1)
                         | ((unsigned)(a2 | (j + 2 == i)) << 2)
                         | ((unsigned)(a3 | (j + 3 == i)) << 3);
            unsigned pn = __shfl_xor(nib, 1, 64);
            if (!(lane & 1))
                brow[it * 32 + (lane >> 1)] = (unsigned char)(nib | (pn << 4));
        }
#pragma unroll
        for (int off = 32; off > 0; off >>= 1) cnt += __shfl_down(cnt, off, 64);
        if (lane == 0) dinv[row] = rsqrtf((float)(cnt + 1));  // +1 self-loop
    }
    if (threadIdx.x < 11) {
        int t = bid * 11 + threadIdx.x;  // 0..22527
        const float* W; bf16* T; int K; int local;
        if (t < 16384)      { W = W0; T = T0; K = NN; local = t; }
        else if (t < 18432) { W = W1; T = T1; K = GH; local = t - 16384; }
        else if (t < 20480) { W = W2; T = T2; K = GH; local = t - 18432; }
        else                { W = W3; T = T3; K = GH; local = t - 20480; }
        int n = local & 127, k0 = (local >> 7) * 8;
        bf16x8 o;
#pragma unroll
        for (int ii = 0; ii < 8; ++ii) o[ii] = (bf16)W[(size_t)(k0 + ii) * GH + n];
        *reinterpret_cast<bf16x8*>(T + (size_t)n * K + k0) = o;
    }
}

// ---------------- gemm3: Xt = (D * aa @ Wt0)^T ; M=32 tile, 2 row-groups per B-frag ----------------
// grid 256 x 512 thr; A (f32->bf16) staged in 64KB swizzled LDS; per f: 1 B-load + 2 MFMA.
__global__ __launch_bounds__(512, 4) void gemm3_kernel(const float* __restrict__ aa,
                                                       const bf16* __restrict__ Wt,
                                                       const float* __restrict__ dinv,
                                                       bf16* __restrict__ Zt) {
    __shared__ bf16 Alds[32768];  // 64KB: [32 rows][128 units]; unit u at u^(row&7)
    int tid = threadIdx.x;
    int wave = tid >> 6, lane = tid & 63;
    int lrow = lane & 15, lg = lane >> 4;
    int lb = (blockIdx.x & 7) * 32 + (blockIdx.x >> 3);  // bijective; batch = bid%8 = XCD
    int m0 = lb * 32;
#pragma unroll
    for (int i = 0; i < 8; ++i) {
        int idx = i * 512 + tid;
        int row = idx >> 7, u = idx & 127;
        const float* src = aa + (size_t)(m0 + row) * NN + u * 8;
        float4 f0 = *reinterpret_cast<const float4*>(src);
        float4 f1 = *reinterpret_cast<const float4*>(src + 4);
        bf16x8 v;
        v[0] = (bf16)f0.x; v[1] = (bf16)f0.y; v[2] = (bf16)f0.z; v[3] = (bf16)f0.w;
        v[4] = (bf16)f1.x; v[5] = (bf16)f1.y; v[6] = (bf16)f1.z; v[7] = (bf16)f1.w;
        *reinterpret_cast<bf16x8*>(&Alds[(row * 128 + (u ^ (row & 7))) * 8]) = v;
    }
    __syncthreads();
    int c0 = wave * 16;
    const bf16* Bp = Wt + (size_t)(c0 + lrow) * NN + lg * 8;
    f32x4 acc[2][2] = {};
#pragma unroll
    for (int f = 0; f < 32; ++f) {
        bf16x8 bb = *reinterpret_cast<const bf16x8*>(Bp + f * 32);
        int u = f * 4 + lg;
#pragma unroll
        for (int rg = 0; rg < 2; ++rg) {
            int r = rg * 16 + lrow;
            bf16x8 a = *reinterpret_cast<const bf16x8*>(&Alds[(r * 128 + (u ^ (r & 7))) * 8]);
            acc[rg][f & 1] = mfma16(a, bb, acc[rg][f & 1]);
        }
    }
    int rl = lg * 4;
    int col = c0 + lrow;
#pragma unroll
    for (int rg = 0; rg < 2; ++rg) {
        f32x4 s = acc[rg][0] + acc[rg][1];
        int rbase = m0 + rg * 16 + rl;
        float4 d4 = *reinterpret_cast<const float4*>(&dinv[rbase]);
        bf16x4 o;
        o[0] = (bf16)(s[0] * d4.x);
        o[1] = (bf16)(s[1] * d4.y);
        o[2] = (bf16)(s[2] * d4.z);
        o[3] = (bf16)(s[3] * d4.w);
        *reinterpret_cast<bf16x4*>(Zt + (size_t)col * MROWS + rbase) = o;
    }
}

// ---------------- fused3: T = A01_b @ Xt_b ; [U=T@W] ; v = relu(D*U+b) ; M=32, K-halved A ----------------
// grid 256 x 512 thr. A expanded from bits per K-half (32KB live) + dedicated Ths/Tls (R10 lesson).
template <int MODE, bool HASW>
__global__ __launch_bounds__(512, 4) void fused3_kernel(const unsigned char* __restrict__ A01b,
                                                        const bf16* __restrict__ Xt,
                                                        const bf16* __restrict__ Wt,
                                                        const float* __restrict__ dinv,
                                                        const float* __restrict__ bias,
                                                        bf16* __restrict__ Hst,
                                                        float* __restrict__ outp) {
    __shared__ bf16 Alds[16384];  // 32KB: [32 rows][64 units] (one K-half)
    __shared__ bf16 Ths[4096];    // 8KB: 32x128 T hi (dedicated)
    __shared__ bf16 Tls[4096];    // 8KB: T lo
    int tid = threadIdx.x;
    int wave = tid >> 6, lane = tid & 63;
    int lrow = lane & 15, lg = lane >> 4;
    int lb = (blockIdx.x & 7) * 32 + (blockIdx.x >> 3);
    int m0 = lb * 32;
    int b = blockIdx.x & 7;
    int c0 = wave * 16;
    const bf16* Bp = Xt + (size_t)(c0 + lrow) * MROWS + b * NN + lg * 8;
    f32x4 acc[2][2] = {};
    int erow = tid >> 4;                 // expansion: thread's row (0..31)
    int eub  = (tid & 15) * 4;           // 4 units (bytes) per thread per half
    int ers  = erow & 7;
#pragma unroll
    for (int h = 0; h < 2; ++h) {
        if (h) __syncthreads();          // WAR: all half-0 A-reads done before overwrite
        {
            unsigned w = *reinterpret_cast<const unsigned*>(
                A01b + (size_t)(m0 + erow) * 128 + h * 64 + eub);
#pragma unroll
            for (int i = 0; i < 4; ++i) {
                unsigned byte = (w >> (8 * i)) & 0xffu;
                bf16x8 v;
#pragma unroll
                for (int k = 0; k < 8; ++k) v[k] = ((byte >> k) & 1u) ? (bf16)1.f : (bf16)0.f;
                *reinterpret_cast<bf16x8*>(&Alds[(erow * 64 + ((eub + i) ^ ers)) * 8]) = v;
            }
        }
        __syncthreads();
#pragma unroll
        for (int fl = 0; fl < 16; ++fl) {
            int f = h * 16 + fl;
            bf16x8 bb = *reinterpret_cast<const bf16x8*>(Bp + f * 32);
            int ul = fl * 4 + lg;
#pragma unroll
            for (int rg = 0; rg < 2; ++rg) {
                int r = rg * 16 + lrow;
                bf16x8 a = *reinterpret_cast<const bf16x8*>(&Alds[(r * 64 + (ul ^ (r & 7))) * 8]);
                acc[rg][f & 1] = mfma16(a, bb, acc[rg][f & 1]);
            }
        }
    }
    int rl = lg * 4;

    if constexpr (!HASW) {
#pragma unroll
        for (int rg = 0; rg < 2; ++rg) {
            f32x4 s = acc[rg][0] + acc[rg][1];
            int rbase = m0 + rg * 16 + rl;
            float4 d4 = *reinterpret_cast<const float4*>(&dinv[rbase]);
            int col = c0 + lrow;
            float bv = bias[col];
            float v0 = fmaxf(s[0] * d4.x + bv, 0.f);
            float v1 = fmaxf(s[1] * d4.y + bv, 0.f);
            float v2 = fmaxf(s[2] * d4.z + bv, 0.f);
            float v3 = fmaxf(s[3] * d4.w + bv, 0.f);
            float* op = outp + (size_t)rbase * GH + col;
            if (MODE == 0) {
                op[0] = 0.25f * v0; op[GH] = 0.25f * v1;
                op[2 * GH] = 0.25f * v2; op[3 * GH] = 0.25f * v3;
            } else {
                op[0] += 0.25f * v0; op[GH] += 0.25f * v1;
                op[2 * GH] += 0.25f * v2; op[3 * GH] += 0.25f * v3;
            }
            if (MODE != 2) {
                bf16x4 h4;
                h4[0] = (bf16)(v0 * d4.x); h4[1] = (bf16)(v1 * d4.y);
                h4[2] = (bf16)(v2 * d4.z); h4[3] = (bf16)(v3 * d4.w);
                *reinterpret_cast<bf16x4*>(Hst + (size_t)col * MROWS + rbase) = h4;
            }
        }
    } else {
        __syncthreads();  // phase separation before T-writes
        {
            int tcol = c0 + lrow;
#pragma unroll
            for (int rg = 0; rg < 2; ++rg) {
                f32x4 s = acc[rg][0] + acc[rg][1];
#pragma unroll
                for (int r = 0; r < 4; ++r) {
                    int trow = rg * 16 + rl + r;
                    float tv = s[r];
                    bf16 hi = (bf16)tv;
                    int ei = trow * 128 + (tcol ^ ((trow & 7) << 3));
                    Ths[ei] = hi;
                    Tls[ei] = (bf16)(tv - (float)hi);
                }
            }
        }
        __syncthreads();
        // U = T@W; wave owns U cols wave*16..+15; K=128; wv reused across both row-groups
        f32x4 u[2] = {};
        int wcol = c0 + lrow;
#pragma unroll
        for (int ks = 0; ks < 4; ++ks) {
            int e0 = ks * 32 + lg * 8;
            bf16x8 wv = *reinterpret_cast<const bf16x8*>(Wt + (size_t)wcol * GH + e0);
#pragma unroll
            for (int rg = 0; rg < 2; ++rg) {
                int trow2 = rg * 16 + lrow;
                int te = trow2 * 128 + (e0 ^ ((trow2 & 7) << 3));
                bf16x8 thi = *reinterpret_cast<const bf16x8*>(&Ths[te]);
                bf16x8 tlo = *reinterpret_cast<const bf16x8*>(&Tls[te]);
                u[rg] = mfma16(thi, wv, u[rg]);
                u[rg] = mfma16(tlo, wv, u[rg]);
            }
        }
#pragma unroll
        for (int rg = 0; rg < 2; ++rg) {
            int rbase = m0 + rg * 16 + rl;
            float4 d4 = *reinterpret_cast<const float4*>(&dinv[rbase]);
            float bv = bias[wcol];
            float v0 = fmaxf(u[rg][0] * d4.x + bv, 0.f);
            float v1 = fmaxf(u[rg][1] * d4.y + bv, 0.f);
            float v2 = fmaxf(u[rg][2] * d4.z + bv, 0.f);
            float v3 = fmaxf(u[rg][3] * d4.w + bv, 0.f);
            float* op = outp + (size_t)rbase * GH + wcol;
            if (MODE == 0) {
                op[0] = 0.25f * v0; op[GH] = 0.25f * v1;
                op[2 * GH] = 0.25f * v2; op[3 * GH] = 0.25f * v3;
            } else {
                op[0] += 0.25f * v0; op[GH] += 0.25f * v1;
                op[2 * GH] += 0.25f * v2; op[3 * GH] += 0.25f * v3;
            }
            if (MODE != 2) {
                bf16x4 h4;
                h4[0] = (bf16)(v0 * d4.x); h4[1] = (bf16)(v1 * d4.y);
                h4[2] = (bf16)(v2 * d4.z); h4[3] = (bf16)(v3 * d4.w);
                *reinterpret_cast<bf16x4*>(Hst + (size_t)wcol * MROWS + rbase) = h4;
            }
        }
    }
}

extern "C" void kernel_launch(void* const* d_in, const int* in_sizes, int n_in,
                              void* d_out, int out_size, void* d_ws, size_t ws_size,
                              hipStream_t stream) {
    const float* aa    = (const float*)d_in[0];
    const int*   rpa   = (const int*)d_in[1];
    const float* W_in  = (const float*)d_in[2];
    const float* b_in  = (const float*)d_in[3];
    const float* W_h0  = (const float*)d_in[4];
    const float* b_h0  = (const float*)d_in[5];
    const float* W_h1  = (const float*)d_in[6];
    const float* b_h1  = (const float*)d_in[7];
    const float* W_out = (const float*)d_in[8];
    const float* b_out = (const float*)d_in[9];
    float* out = (float*)d_out;

    char* ws = (char*)d_ws;
    size_t off = 0;
    float* dinv = (float*)(ws + off); off += (size_t)MROWS * 4;                     // 32KB
    unsigned char* A01b = (unsigned char*)(ws + off); off += (size_t)MROWS * 128;   // 1MB bitmask
    bf16*  Xt   = (bf16*)(ws + off);  off += (size_t)GH * MROWS * 2;                // 2MB
    bf16*  HstA = (bf16*)(ws + off);  off += (size_t)GH * MROWS * 2;                // 2MB
    bf16*  HstB = (bf16*)(ws + off);  off += (size_t)GH * MROWS * 2;                // 2MB
    bf16*  Wt0  = (bf16*)(ws + off);  off += (size_t)GH * NN * 2;                   // 256KB
    bf16*  Wt1  = (bf16*)(ws + off);  off += (size_t)GH * GH * 2;
    bf16*  Wt2  = (bf16*)(ws + off);  off += (size_t)GH * GH * 2;
    bf16*  Wt3  = (bf16*)(ws + off);  off += (size_t)GH * GH * 2;

    prep_kernel<<<2048, 256, 0, stream>>>(rpa, W_in, W_h0, W_h1, W_out,
                                          A01b, dinv, Wt0, Wt1, Wt2, Wt3);
    gemm3_kernel<<<256, 512, 0, stream>>>(aa, Wt0, dinv, Xt);
    fused3_kernel<0, false><<<256, 512, 0, stream>>>(A01b, Xt,   Wt1, dinv, b_in,  HstA, out);
    fused3_kernel<1, true><<<256, 512, 0, stream>>>(A01b, HstA, Wt1, dinv, b_h0, HstB, out);
    fused3_kernel<1, true><<<256, 512, 0, stream>>>(A01b, HstB, Wt2, dinv, b_h1, HstA, out);
    fused3_kernel<2, true><<<256, 512, 0, stream>>>(A01b, HstA, Wt3, dinv, b_out, HstB, out);
}